// Round 2
// baseline (5530.347 us; speedup 1.0000x reference)
//
#include <hip/hip_runtime.h>
#include <hip/hip_bf16.h>
#include <math.h>

// ---------------- static problem config ----------------
#define NKEYS 13294
#define BATCH 2
#define MROWS (BATCH * NKEYS)   // 26588
#define EDIM  256
#define NHEAD 8
#define HDIM  32
#define LLVL  4
#define PPTS  4
#define FDIM  1024
#define EPSV  1e-5f
// NH*L*P*2 = 256 offset cols, NH*L*P = 128 attn cols

// ---------------- fp32 tiled GEMM: C = A(MxK) @ W(KxN) + bias, optional relu ----------------
// Tile 64x64, BK=16, 256 threads, 4x4 micro-tile per thread.
__global__ __launch_bounds__(256) void gemm_bias_k(
    const float* __restrict__ A, const float* __restrict__ W,
    const float* __restrict__ bias, float* __restrict__ C,
    int M, int N, int K, int relu)
{
    __shared__ float sA[16][64];   // [k][m]
    __shared__ float sB[16][64];   // [k][n]
    const int tid = threadIdx.x;
    const int bm = blockIdx.y * 64;
    const int bn = blockIdx.x * 64;
    const int arow = tid >> 2;          // 0..63
    const int acol = (tid & 3) << 2;    // 0,4,8,12
    const int brow = tid >> 4;          // 0..15
    const int bcol = (tid & 15) << 2;   // 0..60
    const int tx = tid & 15;
    const int ty = tid >> 4;
    const int grow = bm + arow;
    const bool aok = grow < M;
    const float* Aptr = A + (size_t)(aok ? grow : 0) * K + acol;
    const float* Wptr = W + (size_t)brow * N + bn + bcol;

    float acc[4][4];
    #pragma unroll
    for (int i = 0; i < 4; ++i)
        #pragma unroll
        for (int j = 0; j < 4; ++j) acc[i][j] = 0.f;

    for (int k0 = 0; k0 < K; k0 += 16) {
        float4 av = make_float4(0.f, 0.f, 0.f, 0.f);
        if (aok) av = *(const float4*)(Aptr + k0);
        const float4 bv = *(const float4*)(Wptr + (size_t)k0 * N);
        sA[acol + 0][arow] = av.x;
        sA[acol + 1][arow] = av.y;
        sA[acol + 2][arow] = av.z;
        sA[acol + 3][arow] = av.w;
        *(float4*)&sB[brow][bcol] = bv;
        __syncthreads();
        #pragma unroll
        for (int k = 0; k < 16; ++k) {
            const float4 aa = *(const float4*)&sA[k][ty << 2];
            const float4 bb = *(const float4*)&sB[k][tx << 2];
            const float a[4] = {aa.x, aa.y, aa.z, aa.w};
            const float b[4] = {bb.x, bb.y, bb.z, bb.w};
            #pragma unroll
            for (int i = 0; i < 4; ++i)
                #pragma unroll
                for (int j = 0; j < 4; ++j)
                    acc[i][j] = fmaf(a[i], b[j], acc[i][j]);
        }
        __syncthreads();
    }

    const float4 bz = *(const float4*)(bias + bn + (tx << 2));
    #pragma unroll
    for (int i = 0; i < 4; ++i) {
        const int row = bm + (ty << 2) + i;
        if (row < M) {
            float4 o;
            o.x = acc[i][0] + bz.x;
            o.y = acc[i][1] + bz.y;
            o.z = acc[i][2] + bz.z;
            o.w = acc[i][3] + bz.w;
            if (relu) {
                o.x = fmaxf(o.x, 0.f); o.y = fmaxf(o.y, 0.f);
                o.z = fmaxf(o.z, 0.f); o.w = fmaxf(o.w, 0.f);
            }
            *(float4*)(C + (size_t)row * N + bn + (tx << 2)) = o;
        }
    }
}

// ---------------- deformable-attention sampling ----------------
// One block per query (b,n); 256 threads = 8 heads x 32 dims.
// Includes the softmax over the 16 attention logits per head.
__global__ __launch_bounds__(256) void sample_k(
    const float* __restrict__ vbuf,    // (M,256) value = x@Wv+bv, col = h*32+d
    const float* __restrict__ offbuf,  // (M,256) offsets, col = ((h*4+l)*4+p)*2+xy
    const float* __restrict__ awbuf,   // (M,128) logits, col = (h*4+l)*4+p
    const float* __restrict__ ref,     // (B,N,4,2)
    float* __restrict__ out)           // (M,256)
{
    const int q = blockIdx.x;           // b*NKEYS + n
    const int t = threadIdx.x;
    const int h = t >> 5;
    const int d = t & 31;
    const int b = q / NKEYS;

    // per-head: L*P*2 = 32 offset floats, L*P = 16 logits
    const float* offrow = offbuf + (size_t)q * 256 + h * 32;
    const float* awrow  = awbuf  + (size_t)q * 128 + h * 16;

    float e[16];
    float mx = -1e30f;
    #pragma unroll
    for (int i = 0; i < 16; ++i) { e[i] = awrow[i]; mx = fmaxf(mx, e[i]); }
    float s = 0.f;
    #pragma unroll
    for (int i = 0; i < 16; ++i) { e[i] = expf(e[i] - mx); s += e[i]; }
    const float inv = 1.f / s;

    const float* refq = ref + (size_t)q * 8;

    const int LH[4] = {100, 50, 25, 13};
    const int LW[4] = {100, 50, 25, 13};
    const int LS[4] = {0, 10000, 12500, 13125};

    float acc = 0.f;
    #pragma unroll
    for (int l = 0; l < 4; ++l) {
        const int hh = LH[l], ww = LW[l];
        // (ref + off/w)*w - 0.5 == ref*w + off - 0.5
        const float rx = refq[l * 2 + 0] * (float)ww - 0.5f;
        const float ry = refq[l * 2 + 1] * (float)hh - 0.5f;
        const float* vlev = vbuf + ((size_t)(b * NKEYS + LS[l])) * 256 + h * 32 + d;
        #pragma unroll
        for (int p = 0; p < 4; ++p) {
            const float x = rx + offrow[(l * 4 + p) * 2 + 0];
            const float y = ry + offrow[(l * 4 + p) * 2 + 1];
            const float x0f = floorf(x), y0f = floorf(y);
            const float lx = x - x0f, ly = y - y0f;
            const int x0 = (int)x0f, y0 = (int)y0f;
            const float aw  = e[l * 4 + p] * inv;
            const float w00 = (1.f - lx) * (1.f - ly) * aw;
            const float w01 = lx * (1.f - ly) * aw;
            const float w10 = (1.f - lx) * ly * aw;
            const float w11 = lx * ly * aw;
            const bool y0ok = (y0 >= 0) & (y0 < hh);
            const bool y1ok = (y0 + 1 >= 0) & (y0 + 1 < hh);
            const bool x0ok = (x0 >= 0) & (x0 < ww);
            const bool x1ok = (x0 + 1 >= 0) & (x0 + 1 < ww);
            if (y0ok && x0ok) acc += w00 * vlev[(size_t)(y0 * ww + x0) * 256];
            if (y0ok && x1ok) acc += w01 * vlev[(size_t)(y0 * ww + x0 + 1) * 256];
            if (y1ok && x0ok) acc += w10 * vlev[(size_t)((y0 + 1) * ww + x0) * 256];
            if (y1ok && x1ok) acc += w11 * vlev[(size_t)((y0 + 1) * ww + x0 + 1) * 256];
        }
    }
    out[(size_t)q * 256 + t] = acc;
}

// ---------------- residual + LayerNorm, one wave per row ----------------
__global__ __launch_bounds__(64) void add_ln_k(
    const float* __restrict__ x, const float* __restrict__ r,
    const float* __restrict__ g, const float* __restrict__ bta,
    float* __restrict__ out)
{
    const int row = blockIdx.x;
    const int t = threadIdx.x;
    const size_t base = (size_t)row * 256 + t * 4;
    const float4 xv = *(const float4*)(x + base);
    const float4 rv = *(const float4*)(r + base);
    float v[4] = {xv.x + rv.x, xv.y + rv.y, xv.z + rv.z, xv.w + rv.w};
    float s = v[0] + v[1] + v[2] + v[3];
    #pragma unroll
    for (int o = 32; o > 0; o >>= 1) s += __shfl_xor(s, o, 64);
    const float m = s * (1.f / 256.f);
    float sq = 0.f;
    #pragma unroll
    for (int i = 0; i < 4; ++i) { const float dd = v[i] - m; sq += dd * dd; }
    #pragma unroll
    for (int o = 32; o > 0; o >>= 1) sq += __shfl_xor(sq, o, 64);
    const float rstd = rsqrtf(sq * (1.f / 256.f) + EPSV);
    const float4 gv = *(const float4*)(g + t * 4);
    const float4 bv = *(const float4*)(bta + t * 4);
    float4 o4;
    o4.x = (v[0] - m) * rstd * gv.x + bv.x;
    o4.y = (v[1] - m) * rstd * gv.y + bv.y;
    o4.z = (v[2] - m) * rstd * gv.z + bv.z;
    o4.w = (v[3] - m) * rstd * gv.w + bv.w;
    *(float4*)(out + base) = o4;
}

// ---------------- host ----------------
static inline void gemm(const float* A, const float* W, const float* b, float* C,
                        int M, int N, int K, int relu, hipStream_t s)
{
    dim3 grid(N / 64, (M + 63) / 64);
    gemm_bias_k<<<grid, 256, 0, s>>>(A, W, b, C, M, N, K, relu);
}

extern "C" void kernel_launch(void* const* d_in, const int* in_sizes, int n_in,
                              void* d_out, int out_size, void* d_ws, size_t ws_size,
                              hipStream_t stream)
{
    const float* src  = (const float*)d_in[0];
    const float* ref  = (const float*)d_in[1];
    // d_in[2] spatial_shapes, d_in[3] level_start_index: compile-time constants
    const float* Woff = (const float*)d_in[4];   // (256, 256)
    const float* boff = (const float*)d_in[5];
    const float* Waw  = (const float*)d_in[6];   // (256, 128)
    const float* baw  = (const float*)d_in[7];
    const float* Wv   = (const float*)d_in[8];
    const float* bv   = (const float*)d_in[9];
    const float* Wo   = (const float*)d_in[10];
    const float* bo   = (const float*)d_in[11];
    const float* ln1g = (const float*)d_in[12];
    const float* ln1b = (const float*)d_in[13];
    const float* Wf1  = (const float*)d_in[14];
    const float* bf1  = (const float*)d_in[15];
    const float* Wf2  = (const float*)d_in[16];
    const float* bf2  = (const float*)d_in[17];
    const float* ln2g = (const float*)d_in[18];
    const float* ln2b = (const float*)d_in[19];

    float* x = (float*)d_out;                 // (M,256) running activation
    float* ws = (float*)d_ws;
    float* vbuf    = ws;                                  // M*256
    float* offbuf  = vbuf   + (size_t)MROWS * 256;        // M*256
    float* awbuf   = offbuf + (size_t)MROWS * 256;        // M*128
    float* attnbuf = awbuf  + (size_t)MROWS * 128;        // M*256
    float* hbuf    = attnbuf + (size_t)MROWS * 256;       // M*1024

    hipMemcpyAsync(x, src, (size_t)MROWS * 256 * sizeof(float),
                   hipMemcpyDeviceToDevice, stream);

    for (int layer = 0; layer < 6; ++layer) {
        gemm(x, Wv,   bv,   vbuf,   MROWS, 256,  256, 0, stream);
        gemm(x, Woff, boff, offbuf, MROWS, 256,  256, 0, stream);
        gemm(x, Waw,  baw,  awbuf,  MROWS, 128,  256, 0, stream);
        sample_k<<<MROWS, 256, 0, stream>>>(vbuf, offbuf, awbuf, ref, attnbuf);
        gemm(attnbuf, Wo, bo, hbuf, MROWS, 256,  256, 0, stream);
        add_ln_k<<<MROWS, 64, 0, stream>>>(x, hbuf, ln1g, ln1b, x);
        gemm(x, Wf1, bf1, hbuf,    MROWS, 1024, 256, 1, stream);
        gemm(hbuf, Wf2, bf2, attnbuf, MROWS, 256, 1024, 0, stream);
        add_ln_k<<<MROWS, 64, 0, stream>>>(x, attnbuf, ln2g, ln2b, x);
    }
}

// Round 3
// 2895.487 us; speedup vs baseline: 1.9100x; 1.9100x over previous
//
#include <hip/hip_runtime.h>
#include <hip/hip_bf16.h>
#include <math.h>

// ---------------- static problem config ----------------
#define NKEYS 13294
#define BATCH 2
#define MROWS (BATCH * NKEYS)   // 26588
#define EDIM  256
#define FDIM  1024
#define EPSV  1e-5f
#define BK    32

typedef __bf16 bf16x8 __attribute__((ext_vector_type(8)));
typedef float  f32x4  __attribute__((ext_vector_type(4)));

__device__ __forceinline__ void async16(const void* g, void* l) {
    __builtin_amdgcn_global_load_lds(
        (const __attribute__((address_space(1))) void*)g,
        (__attribute__((address_space(3))) void*)l, 16, 0, 0);
}

// ---------------- bf16 MFMA GEMM: C = A(MxK,bf16) @ WT(NxK,bf16)^T + bias ----------------
// 128x128 tile, 256 threads (4 waves as 2x2 of 64x64), 16x16x32 MFMA.
// mode 0: fp32 out (stride N). mode 1: split fused store (N=640) ->
//   col<256: o_v fp32 (stride 256); col<512: o_off fp32 (stride 256); else o_aw fp32 (stride 128)
// mode 3: bf16 out with ReLU (stride N).
__global__ __launch_bounds__(256, 2) void gemm_mfma_k(
    const __hip_bfloat16* __restrict__ A, const __hip_bfloat16* __restrict__ WT,
    const float* __restrict__ bias, void* __restrict__ Cout,
    int M, int N, int K, int mode,
    float* __restrict__ o_v, float* __restrict__ o_off, float* __restrict__ o_aw)
{
    __shared__ __hip_bfloat16 sA[128 * BK];   // [row][k] row-major, 8 KB
    __shared__ __hip_bfloat16 sB[128 * BK];   // [n][k] row-major, 8 KB

    const int tid  = threadIdx.x;
    const int bm   = blockIdx.y * 128;
    const int bn   = blockIdx.x * 128;
    const int lane = tid & 63;
    const int w    = tid >> 6;
    const int wr   = w >> 1, wc = w & 1;
    const int l15  = lane & 15, quad = lane >> 4;

    // staging: thread t covers (row = t>>2 [+64], chunk = t&3), 16B per load
    const int srow  = tid >> 2;
    const int chunk = tid & 3;
    int ga0 = bm + srow;      if (ga0 >= M) ga0 = M - 1;
    int ga1 = bm + srow + 64; if (ga1 >= M) ga1 = M - 1;
    const __hip_bfloat16* Ap0 = A  + (size_t)ga0 * K + chunk * 8;
    const __hip_bfloat16* Ap1 = A  + (size_t)ga1 * K + chunk * 8;
    const __hip_bfloat16* Bp0 = WT + (size_t)(bn + srow) * K + chunk * 8;
    const __hip_bfloat16* Bp1 = WT + (size_t)(bn + srow + 64) * K + chunk * 8;
    __hip_bfloat16* sAd0 = sA + tid * 8;            // = (t>>2)*32 + (t&3)*8
    __hip_bfloat16* sAd1 = sA + 64 * BK + tid * 8;
    __hip_bfloat16* sBd0 = sB + tid * 8;
    __hip_bfloat16* sBd1 = sB + 64 * BK + tid * 8;

    f32x4 acc[4][4];
    #pragma unroll
    for (int i = 0; i < 4; ++i)
        #pragma unroll
        for (int j = 0; j < 4; ++j) acc[i][j] = (f32x4)0.f;

    for (int k0 = 0; k0 < K; k0 += BK) {
        __syncthreads();                       // all waves done reading prev tile
        async16(Ap0 + k0, sAd0);
        async16(Ap1 + k0, sAd1);
        async16(Bp0 + k0, sBd0);
        async16(Bp1 + k0, sBd1);
        __syncthreads();                       // drains vmcnt -> LDS visible

        bf16x8 a[4], b[4];
        #pragma unroll
        for (int mt = 0; mt < 4; ++mt)
            a[mt] = *(const bf16x8*)&sA[(wr * 64 + mt * 16 + l15) * BK + quad * 8];
        #pragma unroll
        for (int nt = 0; nt < 4; ++nt)
            b[nt] = *(const bf16x8*)&sB[(wc * 64 + nt * 16 + l15) * BK + quad * 8];
        #pragma unroll
        for (int mt = 0; mt < 4; ++mt)
            #pragma unroll
            for (int nt = 0; nt < 4; ++nt)
                acc[mt][nt] = __builtin_amdgcn_mfma_f32_16x16x32_bf16(
                    a[mt], b[nt], acc[mt][nt], 0, 0, 0);
    }

    // epilogue: C row = bm + wr*64 + mt*16 + quad*4 + r ; col = bn + wc*64 + nt*16 + l15
    #pragma unroll
    for (int mt = 0; mt < 4; ++mt) {
        #pragma unroll
        for (int nt = 0; nt < 4; ++nt) {
            const int col = bn + wc * 64 + nt * 16 + l15;
            const float bz = bias[col];
            #pragma unroll
            for (int r = 0; r < 4; ++r) {
                const int row = bm + wr * 64 + mt * 16 + quad * 4 + r;
                if (row >= M) continue;
                float vv = acc[mt][nt][r] + bz;
                if (mode == 0) {
                    ((float*)Cout)[(size_t)row * N + col] = vv;
                } else if (mode == 1) {
                    if (col < 256)      o_v  [(size_t)row * 256 + col]        = vv;
                    else if (col < 512) o_off[(size_t)row * 256 + (col - 256)] = vv;
                    else                o_aw [(size_t)row * 128 + (col - 512)] = vv;
                } else { // mode 3: bf16 + relu
                    vv = fmaxf(vv, 0.f);
                    ((__hip_bfloat16*)Cout)[(size_t)row * N + col] = __float2bfloat16(vv);
                }
            }
        }
    }
}

// ---------------- weight transpose+convert: W(KxN f32) -> WT rows [rowOff..rowOff+N) (ldT=K bf16) ----
__global__ void convert_wt_k(const float* __restrict__ W, __hip_bfloat16* __restrict__ WT,
                             int K, int N, int rowOff)
{
    const int idx = blockIdx.x * 256 + threadIdx.x;
    if (idx >= K * N) return;
    const int k = idx / N, n = idx % N;
    WT[(size_t)(rowOff + n) * K + k] = __float2bfloat16(W[idx]);
}

__global__ void pack_bias_k(const float* __restrict__ bv, const float* __restrict__ boff,
                            const float* __restrict__ baw, float* __restrict__ dst)
{
    const int i = blockIdx.x * 256 + threadIdx.x;
    if (i < 256) dst[i] = bv[i];
    else if (i < 512) dst[i] = boff[i - 256];
    else if (i < 640) dst[i] = baw[i - 512];
}

__global__ void convert_src_k(const float* __restrict__ src, float* __restrict__ x,
                              __hip_bfloat16* __restrict__ xb)
{
    const int i = blockIdx.x * 256 + threadIdx.x;   // over n/4
    const float4 v = ((const float4*)src)[i];
    ((float4*)x)[i] = v;
    xb[i * 4 + 0] = __float2bfloat16(v.x);
    xb[i * 4 + 1] = __float2bfloat16(v.y);
    xb[i * 4 + 2] = __float2bfloat16(v.z);
    xb[i * 4 + 3] = __float2bfloat16(v.w);
}

// ---------------- deformable-attention sampling (fp32 in, bf16 out) ----------------
__global__ __launch_bounds__(256) void sample_k(
    const float* __restrict__ vbuf,    // (M,256) col = h*32+d
    const float* __restrict__ offbuf,  // (M,256) col = ((h*4+l)*4+p)*2+xy
    const float* __restrict__ awbuf,   // (M,128) col = (h*4+l)*4+p
    const float* __restrict__ ref,     // (B,N,4,2)
    __hip_bfloat16* __restrict__ out)  // (M,256) bf16
{
    const int q = blockIdx.x;
    const int t = threadIdx.x;
    const int h = t >> 5;
    const int d = t & 31;
    const int b = q / NKEYS;

    const float* offrow = offbuf + (size_t)q * 256 + h * 32;
    const float* awrow  = awbuf  + (size_t)q * 128 + h * 16;

    float e[16];
    float mx = -1e30f;
    #pragma unroll
    for (int i = 0; i < 16; ++i) { e[i] = awrow[i]; mx = fmaxf(mx, e[i]); }
    float s = 0.f;
    #pragma unroll
    for (int i = 0; i < 16; ++i) { e[i] = expf(e[i] - mx); s += e[i]; }
    const float inv = 1.f / s;

    const float* refq = ref + (size_t)q * 8;
    const int LH[4] = {100, 50, 25, 13};
    const int LW[4] = {100, 50, 25, 13};
    const int LS[4] = {0, 10000, 12500, 13125};

    float acc = 0.f;
    #pragma unroll
    for (int l = 0; l < 4; ++l) {
        const int hh = LH[l], ww = LW[l];
        const float rx = refq[l * 2 + 0] * (float)ww - 0.5f;
        const float ry = refq[l * 2 + 1] * (float)hh - 0.5f;
        const float* vlev = vbuf + ((size_t)(b * NKEYS + LS[l])) * 256 + h * 32 + d;
        #pragma unroll
        for (int p = 0; p < 4; ++p) {
            const float x = rx + offrow[(l * 4 + p) * 2 + 0];
            const float y = ry + offrow[(l * 4 + p) * 2 + 1];
            const float x0f = floorf(x), y0f = floorf(y);
            const float lx = x - x0f, ly = y - y0f;
            const int x0 = (int)x0f, y0 = (int)y0f;
            const float aw  = e[l * 4 + p] * inv;
            const float w00 = (1.f - lx) * (1.f - ly) * aw;
            const float w01 = lx * (1.f - ly) * aw;
            const float w10 = (1.f - lx) * ly * aw;
            const float w11 = lx * ly * aw;
            const bool y0ok = (y0 >= 0) & (y0 < hh);
            const bool y1ok = (y0 + 1 >= 0) & (y0 + 1 < hh);
            const bool x0ok = (x0 >= 0) & (x0 < ww);
            const bool x1ok = (x0 + 1 >= 0) & (x0 + 1 < ww);
            if (y0ok && x0ok) acc += w00 * vlev[(size_t)(y0 * ww + x0) * 256];
            if (y0ok && x1ok) acc += w01 * vlev[(size_t)(y0 * ww + x0 + 1) * 256];
            if (y1ok && x0ok) acc += w10 * vlev[(size_t)((y0 + 1) * ww + x0) * 256];
            if (y1ok && x1ok) acc += w11 * vlev[(size_t)((y0 + 1) * ww + x0 + 1) * 256];
        }
    }
    out[(size_t)q * 256 + t] = __float2bfloat16(acc);
}

// ---------------- residual + LayerNorm (writes fp32 x AND bf16 xb) ----------------
__global__ __launch_bounds__(64) void add_ln_k(
    const float* __restrict__ x, const float* __restrict__ r,
    const float* __restrict__ g, const float* __restrict__ bta,
    float* __restrict__ out, __hip_bfloat16* __restrict__ outb)
{
    const int row = blockIdx.x;
    const int t = threadIdx.x;
    const size_t base = (size_t)row * 256 + t * 4;
    const float4 xv = *(const float4*)(x + base);
    const float4 rv = *(const float4*)(r + base);
    float v[4] = {xv.x + rv.x, xv.y + rv.y, xv.z + rv.z, xv.w + rv.w};
    float s = v[0] + v[1] + v[2] + v[3];
    #pragma unroll
    for (int o = 32; o > 0; o >>= 1) s += __shfl_xor(s, o, 64);
    const float m = s * (1.f / 256.f);
    float sq = 0.f;
    #pragma unroll
    for (int i = 0; i < 4; ++i) { const float dd = v[i] - m; sq += dd * dd; }
    #pragma unroll
    for (int o = 32; o > 0; o >>= 1) sq += __shfl_xor(sq, o, 64);
    const float rstd = rsqrtf(sq * (1.f / 256.f) + EPSV);
    const float4 gv = *(const float4*)(g + t * 4);
    const float4 bv = *(const float4*)(bta + t * 4);
    float4 o4;
    o4.x = (v[0] - m) * rstd * gv.x + bv.x;
    o4.y = (v[1] - m) * rstd * gv.y + bv.y;
    o4.z = (v[2] - m) * rstd * gv.z + bv.z;
    o4.w = (v[3] - m) * rstd * gv.w + bv.w;
    *(float4*)(out + base) = o4;
    outb[base + 0] = __float2bfloat16(o4.x);
    outb[base + 1] = __float2bfloat16(o4.y);
    outb[base + 2] = __float2bfloat16(o4.z);
    outb[base + 3] = __float2bfloat16(o4.w);
}

// ---------------- host ----------------
extern "C" void kernel_launch(void* const* d_in, const int* in_sizes, int n_in,
                              void* d_out, int out_size, void* d_ws, size_t ws_size,
                              hipStream_t stream)
{
    const float* src  = (const float*)d_in[0];
    const float* ref  = (const float*)d_in[1];
    const float* Woff = (const float*)d_in[4];   // (256,256)
    const float* boff = (const float*)d_in[5];
    const float* Waw  = (const float*)d_in[6];   // (256,128)
    const float* baw  = (const float*)d_in[7];
    const float* Wv   = (const float*)d_in[8];   // (256,256)
    const float* bv   = (const float*)d_in[9];
    const float* Wo   = (const float*)d_in[10];  // (256,256)
    const float* bo   = (const float*)d_in[11];
    const float* ln1g = (const float*)d_in[12];
    const float* ln1b = (const float*)d_in[13];
    const float* Wf1  = (const float*)d_in[14];  // (256,1024)
    const float* bf1  = (const float*)d_in[15];
    const float* Wf2  = (const float*)d_in[16];  // (1024,256)
    const float* bf2  = (const float*)d_in[17];
    const float* ln2g = (const float*)d_in[18];
    const float* ln2b = (const float*)d_in[19];

    float* x = (float*)d_out;                     // (M,256) running activation fp32

    // workspace layout: fp32 region then bf16 region
    float* ws = (float*)d_ws;
    float* vbuf   = ws;                                   // M*256 f32
    float* offbuf = vbuf   + (size_t)MROWS * 256;         // M*256 f32
    float* awbuf  = offbuf + (size_t)MROWS * 256;         // M*128 f32
    float* obuf   = awbuf  + (size_t)MROWS * 128;         // M*256 f32
    float* bias1  = obuf   + (size_t)MROWS * 256;         // 640 f32
    __hip_bfloat16* xb    = (__hip_bfloat16*)(bias1 + 640);
    __hip_bfloat16* attnb = xb    + (size_t)MROWS * 256;  // M*256 bf16
    __hip_bfloat16* hb    = attnb + (size_t)MROWS * 256;  // M*1024 bf16
    __hip_bfloat16* WT1   = hb    + (size_t)MROWS * 1024; // 640*256
    __hip_bfloat16* WTo   = WT1   + 640 * 256;            // 256*256
    __hip_bfloat16* WTf1  = WTo   + 256 * 256;            // 1024*256
    __hip_bfloat16* WTf2  = WTf1  + 1024 * 256;           // 256*1024

    // ---- per-call prep (weights re-poisoned each call; tiny cost) ----
    convert_wt_k<<<(256 * 256 + 255) / 256, 256, 0, stream>>>(Wv,   WT1,  256, 256,   0);
    convert_wt_k<<<(256 * 256 + 255) / 256, 256, 0, stream>>>(Woff, WT1,  256, 256, 256);
    convert_wt_k<<<(256 * 128 + 255) / 256, 256, 0, stream>>>(Waw,  WT1,  256, 128, 512);
    convert_wt_k<<<(256 * 256 + 255) / 256, 256, 0, stream>>>(Wo,   WTo,  256, 256,   0);
    convert_wt_k<<<(256 * 1024 + 255) / 256, 256, 0, stream>>>(Wf1, WTf1, 256, 1024,  0);
    convert_wt_k<<<(1024 * 256 + 255) / 256, 256, 0, stream>>>(Wf2, WTf2, 1024, 256,  0);
    pack_bias_k<<<3, 256, 0, stream>>>(bv, boff, baw, bias1);
    convert_src_k<<<(MROWS * 64 + 255) / 256, 256, 0, stream>>>(src, x, xb);

    const int gy = (MROWS + 127) / 128;   // 208
    for (int layer = 0; layer < 6; ++layer) {
        // fused value/offset/logit GEMM: (M,256)@(256,640)
        gemm_mfma_k<<<dim3(640 / 128, gy), 256, 0, stream>>>(
            xb, WT1, bias1, nullptr, MROWS, 640, 256, 1, vbuf, offbuf, awbuf);
        sample_k<<<MROWS, 256, 0, stream>>>(vbuf, offbuf, awbuf, ref, attnb);
        gemm_mfma_k<<<dim3(256 / 128, gy), 256, 0, stream>>>(
            attnb, WTo, bo, obuf, MROWS, 256, 256, 0, nullptr, nullptr, nullptr);
        add_ln_k<<<MROWS, 64, 0, stream>>>(x, obuf, ln1g, ln1b, x, xb);
        gemm_mfma_k<<<dim3(1024 / 128, gy), 256, 0, stream>>>(
            xb, WTf1, bf1, hb, MROWS, 1024, 256, 3, nullptr, nullptr, nullptr);
        gemm_mfma_k<<<dim3(256 / 128, gy), 256, 0, stream>>>(
            hb, WTf2, bf2, obuf, MROWS, 256, 1024, 0, nullptr, nullptr, nullptr);
        add_ln_k<<<MROWS, 64, 0, stream>>>(x, obuf, ln2g, ln2b, x, xb);
    }
}

// Round 4
// 2507.921 us; speedup vs baseline: 2.2052x; 1.1545x over previous
//
#include <hip/hip_runtime.h>
#include <hip/hip_bf16.h>
#include <math.h>

// ---------------- static problem config ----------------
#define NKEYS 13294
#define BATCH 2
#define MROWS (BATCH * NKEYS)   // 26588
#define EDIM  256
#define FDIM  1024
#define EPSV  1e-5f
#define BK    32

typedef __bf16 bf16x8 __attribute__((ext_vector_type(8)));
typedef float  f32x4  __attribute__((ext_vector_type(4)));

__device__ __forceinline__ void async16(const void* g, void* l) {
    __builtin_amdgcn_global_load_lds(
        (const __attribute__((address_space(1))) void*)g,
        (__attribute__((address_space(3))) void*)l, 16, 0, 0);
}

// ---------------- bf16 MFMA GEMM: C = A(MxK,bf16) @ WT(NxK,bf16)^T + bias ----------------
// 128x128 tile, 256 threads (4 waves as 2x2 of 64x64), 16x16x32 MFMA.
// mode 0: fp32 out (stride N).
// mode 1: split fused store (N=640):
//   col<256: value -> v_t head-major (b*8+h, key, 32) fp32
//   col<512: o_off fp32 (stride 256); else o_aw fp32 (stride 128)
// mode 3: bf16 out with ReLU (stride N).
__global__ __launch_bounds__(256, 2) void gemm_mfma_k(
    const __hip_bfloat16* __restrict__ A, const __hip_bfloat16* __restrict__ WT,
    const float* __restrict__ bias, void* __restrict__ Cout,
    int M, int N, int K, int mode,
    float* __restrict__ o_v, float* __restrict__ o_off, float* __restrict__ o_aw)
{
    __shared__ __hip_bfloat16 sA[128 * BK];   // [row][k] row-major, 8 KB
    __shared__ __hip_bfloat16 sB[128 * BK];   // [n][k] row-major, 8 KB

    const int tid  = threadIdx.x;
    const int bm   = blockIdx.y * 128;
    const int bn   = blockIdx.x * 128;
    const int lane = tid & 63;
    const int w    = tid >> 6;
    const int wr   = w >> 1, wc = w & 1;
    const int l15  = lane & 15, quad = lane >> 4;

    const int srow  = tid >> 2;
    const int chunk = tid & 3;
    int ga0 = bm + srow;      if (ga0 >= M) ga0 = M - 1;
    int ga1 = bm + srow + 64; if (ga1 >= M) ga1 = M - 1;
    const __hip_bfloat16* Ap0 = A  + (size_t)ga0 * K + chunk * 8;
    const __hip_bfloat16* Ap1 = A  + (size_t)ga1 * K + chunk * 8;
    const __hip_bfloat16* Bp0 = WT + (size_t)(bn + srow) * K + chunk * 8;
    const __hip_bfloat16* Bp1 = WT + (size_t)(bn + srow + 64) * K + chunk * 8;
    __hip_bfloat16* sAd0 = sA + tid * 8;
    __hip_bfloat16* sAd1 = sA + 64 * BK + tid * 8;
    __hip_bfloat16* sBd0 = sB + tid * 8;
    __hip_bfloat16* sBd1 = sB + 64 * BK + tid * 8;

    f32x4 acc[4][4];
    #pragma unroll
    for (int i = 0; i < 4; ++i)
        #pragma unroll
        for (int j = 0; j < 4; ++j) acc[i][j] = (f32x4)0.f;

    for (int k0 = 0; k0 < K; k0 += BK) {
        __syncthreads();
        async16(Ap0 + k0, sAd0);
        async16(Ap1 + k0, sAd1);
        async16(Bp0 + k0, sBd0);
        async16(Bp1 + k0, sBd1);
        __syncthreads();

        bf16x8 a[4], b[4];
        #pragma unroll
        for (int mt = 0; mt < 4; ++mt)
            a[mt] = *(const bf16x8*)&sA[(wr * 64 + mt * 16 + l15) * BK + quad * 8];
        #pragma unroll
        for (int nt = 0; nt < 4; ++nt)
            b[nt] = *(const bf16x8*)&sB[(wc * 64 + nt * 16 + l15) * BK + quad * 8];
        #pragma unroll
        for (int mt = 0; mt < 4; ++mt)
            #pragma unroll
            for (int nt = 0; nt < 4; ++nt)
                acc[mt][nt] = __builtin_amdgcn_mfma_f32_16x16x32_bf16(
                    a[mt], b[nt], acc[mt][nt], 0, 0, 0);
    }

    #pragma unroll
    for (int mt = 0; mt < 4; ++mt) {
        #pragma unroll
        for (int nt = 0; nt < 4; ++nt) {
            const int col = bn + wc * 64 + nt * 16 + l15;
            const float bz = bias[col];
            #pragma unroll
            for (int r = 0; r < 4; ++r) {
                const int row = bm + wr * 64 + mt * 16 + quad * 4 + r;
                if (row >= M) continue;
                float vv = acc[mt][nt][r] + bz;
                if (mode == 0) {
                    ((float*)Cout)[(size_t)row * N + col] = vv;
                } else if (mode == 1) {
                    if (col < 256) {
                        // head-major transpose: idx = ((b*7+h)*NKEYS + row)*32 + d
                        const int b = (row >= NKEYS) ? 1 : 0;
                        const int h = col >> 5, d = col & 31;
                        o_v[((size_t)(b * 7 + h) * NKEYS + row) * 32 + d] = vv;
                    } else if (col < 512) {
                        o_off[(size_t)row * 256 + (col - 256)] = vv;
                    } else {
                        o_aw[(size_t)row * 128 + (col - 512)] = vv;
                    }
                } else { // mode 3: bf16 + relu
                    vv = fmaxf(vv, 0.f);
                    ((__hip_bfloat16*)Cout)[(size_t)row * N + col] = __float2bfloat16(vv);
                }
            }
        }
    }
}

// ---------------- weight transpose+convert ----------------
__global__ void convert_wt_k(const float* __restrict__ W, __hip_bfloat16* __restrict__ WT,
                             int K, int N, int rowOff)
{
    const int idx = blockIdx.x * 256 + threadIdx.x;
    if (idx >= K * N) return;
    const int k = idx / N, n = idx % N;
    WT[(size_t)(rowOff + n) * K + k] = __float2bfloat16(W[idx]);
}

__global__ void pack_bias_k(const float* __restrict__ bv, const float* __restrict__ boff,
                            const float* __restrict__ baw, float* __restrict__ dst)
{
    const int i = blockIdx.x * 256 + threadIdx.x;
    if (i < 256) dst[i] = bv[i];
    else if (i < 512) dst[i] = boff[i - 256];
    else if (i < 640) dst[i] = baw[i - 512];
}

__global__ void convert_src_k(const float* __restrict__ src, float* __restrict__ x,
                              __hip_bfloat16* __restrict__ xb)
{
    const int i = blockIdx.x * 256 + threadIdx.x;   // over n/4
    const float4 v = ((const float4*)src)[i];
    ((float4*)x)[i] = v;
    xb[i * 4 + 0] = __float2bfloat16(v.x);
    xb[i * 4 + 1] = __float2bfloat16(v.y);
    xb[i * 4 + 2] = __float2bfloat16(v.z);
    xb[i * 4 + 3] = __float2bfloat16(v.w);
}

// ---------------- deformable-attention sampling, 2-phase ----------------
// Block = 2 queries, 256 threads.
// Phase 1: thread t -> (qi=t>>7, h=(t>>4)&7, i=t&15): softmax over 16 logits
//   (16-lane shuffle groups), bilinear weights+addresses once -> LDS.
// Phase 2: thread t -> (h=t>>5, d=t&31): 16 samples/query, 4 gathers each,
//   weights broadcast from LDS.
__global__ __launch_bounds__(256) void sample_k(
    const float* __restrict__ v_t,     // (B*8, NKEYS, 32) f32 head-major
    const float* __restrict__ offbuf,  // (M,256) col = (h*16+i)*2+xy
    const float* __restrict__ awbuf,   // (M,128) col = h*16+i
    const float* __restrict__ ref,     // (M,4,2)
    __hip_bfloat16* __restrict__ out)  // (M,256)
{
    __shared__ float sw[256][4];
    __shared__ int   sa[256][4];
    const int t  = threadIdx.x;
    const int q0 = blockIdx.x * 2;

    // ---- phase 1 ----
    {
        const int qi = t >> 7, h = (t >> 4) & 7, i = t & 15;
        const int q = q0 + qi;
        const int l = i >> 2;
        const float logit = awbuf[(size_t)q * 128 + h * 16 + i];
        float mx = logit;
        #pragma unroll
        for (int m = 1; m < 16; m <<= 1) mx = fmaxf(mx, __shfl_xor(mx, m, 64));
        const float e = __expf(logit - mx);
        float s = e;
        #pragma unroll
        for (int m = 1; m < 16; m <<= 1) s += __shfl_xor(s, m, 64);
        const float aw = e / s;

        const int ww = (l == 0) ? 100 : (l == 1) ? 50 : (l == 2) ? 25 : 13;
        const int ls = (l == 0) ? 0 : (l == 1) ? 10000 : (l == 2) ? 12500 : 13125;
        const int b  = (q >= NKEYS) ? 1 : 0;
        const int slab = (b * 8 + h) * NKEYS + ls;

        const float2 off = *(const float2*)&offbuf[(size_t)q * 256 + h * 32 + i * 2];
        const float2 rf  = *(const float2*)&ref[(size_t)q * 8 + l * 2];
        const float x = rf.x * (float)ww + off.x - 0.5f;
        const float y = rf.y * (float)ww + off.y - 0.5f;   // ww==hh per level
        const float x0f = floorf(x), y0f = floorf(y);
        const float lx = x - x0f, ly = y - y0f;
        const int x0 = (int)x0f, y0 = (int)y0f;
        const bool x0ok = (x0 >= 0) & (x0 < ww);
        const bool x1ok = (x0 + 1 >= 0) & (x0 + 1 < ww);
        const bool y0ok = (y0 >= 0) & (y0 < ww);
        const bool y1ok = (y0 + 1 >= 0) & (y0 + 1 < ww);

        float w00 = (1.f - lx) * (1.f - ly) * aw;
        float w01 = lx * (1.f - ly) * aw;
        float w10 = (1.f - lx) * ly * aw;
        float w11 = lx * ly * aw;
        int a00 = slab + y0 * ww + x0;
        int a01 = a00 + 1;
        int a10 = a00 + ww;
        int a11 = a10 + 1;
        if (!(y0ok & x0ok)) { w00 = 0.f; a00 = 0; }
        if (!(y0ok & x1ok)) { w01 = 0.f; a01 = 0; }
        if (!(y1ok & x0ok)) { w10 = 0.f; a10 = 0; }
        if (!(y1ok & x1ok)) { w11 = 0.f; a11 = 0; }

        sw[t][0] = w00; sw[t][1] = w01; sw[t][2] = w10; sw[t][3] = w11;
        sa[t][0] = a00; sa[t][1] = a01; sa[t][2] = a10; sa[t][3] = a11;
    }
    __syncthreads();

    // ---- phase 2 ----
    const int h = t >> 5, d = t & 31;
    #pragma unroll
    for (int qi = 0; qi < 2; ++qi) {
        const int ebase = qi * 128 + h * 16;
        float acc = 0.f;
        #pragma unroll
        for (int i = 0; i < 16; ++i) {
            const f32x4 wv = *(const f32x4*)sw[ebase + i];
            const int4  av = *(const int4*)sa[ebase + i];
            acc += wv[0] * v_t[(size_t)av.x * 32 + d];
            acc += wv[1] * v_t[(size_t)av.y * 32 + d];
            acc += wv[2] * v_t[(size_t)av.z * 32 + d];
            acc += wv[3] * v_t[(size_t)av.w * 32 + d];
        }
        out[(size_t)(q0 + qi) * 256 + t] = __float2bfloat16(acc);
    }
}

// ---------------- residual + LayerNorm (writes fp32 x AND bf16 xb) ----------------
__global__ __launch_bounds__(64) void add_ln_k(
    const float* __restrict__ x, const float* __restrict__ r,
    const float* __restrict__ g, const float* __restrict__ bta,
    float* __restrict__ out, __hip_bfloat16* __restrict__ outb)
{
    const int row = blockIdx.x;
    const int t = threadIdx.x;
    const size_t base = (size_t)row * 256 + t * 4;
    const float4 xv = *(const float4*)(x + base);
    const float4 rv = *(const float4*)(r + base);
    float v[4] = {xv.x + rv.x, xv.y + rv.y, xv.z + rv.z, xv.w + rv.w};
    float s = v[0] + v[1] + v[2] + v[3];
    #pragma unroll
    for (int o = 32; o > 0; o >>= 1) s += __shfl_xor(s, o, 64);
    const float m = s * (1.f / 256.f);
    float sq = 0.f;
    #pragma unroll
    for (int i = 0; i < 4; ++i) { const float dd = v[i] - m; sq += dd * dd; }
    #pragma unroll
    for (int o = 32; o > 0; o >>= 1) sq += __shfl_xor(sq, o, 64);
    const float rstd = rsqrtf(sq * (1.f / 256.f) + EPSV);
    const float4 gv = *(const float4*)(g + t * 4);
    const float4 bv = *(const float4*)(bta + t * 4);
    float4 o4;
    o4.x = (v[0] - m) * rstd * gv.x + bv.x;
    o4.y = (v[1] - m) * rstd * gv.y + bv.y;
    o4.z = (v[2] - m) * rstd * gv.z + bv.z;
    o4.w = (v[3] - m) * rstd * gv.w + bv.w;
    *(float4*)(out + base) = o4;
    outb[base + 0] = __float2bfloat16(o4.x);
    outb[base + 1] = __float2bfloat16(o4.y);
    outb[base + 2] = __float2bfloat16(o4.z);
    outb[base + 3] = __float2bfloat16(o4.w);
}

// ---------------- host ----------------
extern "C" void kernel_launch(void* const* d_in, const int* in_sizes, int n_in,
                              void* d_out, int out_size, void* d_ws, size_t ws_size,
                              hipStream_t stream)
{
    const float* src  = (const float*)d_in[0];
    const float* ref  = (const float*)d_in[1];
    const float* Woff = (const float*)d_in[4];   // (256,256)
    const float* boff = (const float*)d_in[5];
    const float* Waw  = (const float*)d_in[6];   // (256,128)
    const float* baw  = (const float*)d_in[7];
    const float* Wv   = (const float*)d_in[8];   // (256,256)
    const float* bv   = (const float*)d_in[9];
    const float* Wo   = (const float*)d_in[10];  // (256,256)
    const float* bo   = (const float*)d_in[11];
    const float* ln1g = (const float*)d_in[12];
    const float* ln1b = (const float*)d_in[13];
    const float* Wf1  = (const float*)d_in[14];  // (256,1024)
    const float* bf1  = (const float*)d_in[15];
    const float* Wf2  = (const float*)d_in[16];  // (1024,256)
    const float* bf2  = (const float*)d_in[17];
    const float* ln2g = (const float*)d_in[18];
    const float* ln2b = (const float*)d_in[19];

    float* x = (float*)d_out;                     // (M,256) fp32 running activation

    float* ws = (float*)d_ws;
    float* v_t    = ws;                                   // M*256 f32 (head-major)
    float* offbuf = v_t    + (size_t)MROWS * 256;         // M*256 f32
    float* awbuf  = offbuf + (size_t)MROWS * 256;         // M*128 f32
    float* obuf   = awbuf  + (size_t)MROWS * 128;         // M*256 f32
    float* bias1  = obuf   + (size_t)MROWS * 256;         // 640 f32
    __hip_bfloat16* xb    = (__hip_bfloat16*)(bias1 + 640);
    __hip_bfloat16* attnb = xb    + (size_t)MROWS * 256;  // M*256 bf16
    __hip_bfloat16* hb    = attnb + (size_t)MROWS * 256;  // M*1024 bf16
    __hip_bfloat16* WT1   = hb    + (size_t)MROWS * 1024; // 640*256
    __hip_bfloat16* WTo   = WT1   + 640 * 256;            // 256*256
    __hip_bfloat16* WTf1  = WTo   + 256 * 256;            // 1024*256
    __hip_bfloat16* WTf2  = WTf1  + 1024 * 256;           // 256*1024

    convert_wt_k<<<(256 * 256 + 255) / 256, 256, 0, stream>>>(Wv,   WT1,  256, 256,   0);
    convert_wt_k<<<(256 * 256 + 255) / 256, 256, 0, stream>>>(Woff, WT1,  256, 256, 256);
    convert_wt_k<<<(256 * 128 + 255) / 256, 256, 0, stream>>>(Waw,  WT1,  256, 128, 512);
    convert_wt_k<<<(256 * 256 + 255) / 256, 256, 0, stream>>>(Wo,   WTo,  256, 256,   0);
    convert_wt_k<<<(256 * 1024 + 255) / 256, 256, 0, stream>>>(Wf1, WTf1, 256, 1024,  0);
    convert_wt_k<<<(1024 * 256 + 255) / 256, 256, 0, stream>>>(Wf2, WTf2, 1024, 256,  0);
    pack_bias_k<<<3, 256, 0, stream>>>(bv, boff, baw, bias1);
    convert_src_k<<<(MROWS * 64 + 255) / 256, 256, 0, stream>>>(src, x, xb);

    const int gy = (MROWS + 127) / 128;   // 208
    for (int layer = 0; layer < 6; ++layer) {
        gemm_mfma_k<<<dim3(640 / 128, gy), 256, 0, stream>>>(
            xb, WT1, bias1, nullptr, MROWS, 640, 256, 1, v_t, offbuf, awbuf);
        sample_k<<<MROWS / 2, 256, 0, stream>>>(v_t, offbuf, awbuf, ref, attnb);
        gemm_mfma_k<<<dim3(256 / 128, gy), 256, 0, stream>>>(
            attnb, WTo, bo, obuf, MROWS, 256, 256, 0, nullptr, nullptr, nullptr);
        add_ln_k<<<MROWS, 64, 0, stream>>>(x, obuf, ln1g, ln1b, x, xb);
        gemm_mfma_k<<<dim3(1024 / 128, gy), 256, 0, stream>>>(
            xb, WTf1, bf1, hb, MROWS, 1024, 256, 3, nullptr, nullptr, nullptr);
        gemm_mfma_k<<<dim3(256 / 128, gy), 256, 0, stream>>>(
            hb, WTf2, bf2, obuf, MROWS, 256, 1024, 0, nullptr, nullptr, nullptr);
        add_ln_k<<<MROWS, 64, 0, stream>>>(x, obuf, ln2g, ln2b, x, xb);
    }
}

// Round 5
// 1464.640 us; speedup vs baseline: 3.7759x; 1.7123x over previous
//
#include <hip/hip_runtime.h>
#include <hip/hip_bf16.h>
#include <math.h>

// ---------------- static problem config ----------------
#define NKEYS 13294
#define BATCH 2
#define MROWS (BATCH * NKEYS)   // 26588
#define EDIM  256
#define FDIM  1024
#define EPSV  1e-5f
#define BK    32

typedef __bf16 bf16x8 __attribute__((ext_vector_type(8)));
typedef float  f32x4  __attribute__((ext_vector_type(4)));

__device__ __forceinline__ void async16(const void* g, void* l) {
    __builtin_amdgcn_global_load_lds(
        (const __attribute__((address_space(1))) void*)g,
        (__attribute__((address_space(3))) void*)l, 16, 0, 0);
}

// ---------------- bf16 MFMA GEMM: C = A(MxK,bf16) @ WT(NxK,bf16)^T + bias ----------------
// 128x128 tile, 256 threads (4 waves as 2x2 of 64x64), 16x16x32 MFMA.
// mode 0: fp32 out (stride N).
// mode 1: split fused store (N=640):
//   col<256: value -> v_bf bf16 head-major (b*8+h, key, 32)
//   col<512: o_off fp32 (stride 256); else o_aw fp32 (stride 128)
// mode 3: bf16 out with ReLU (stride N).
__global__ __launch_bounds__(256, 2) void gemm_mfma_k(
    const __hip_bfloat16* __restrict__ A, const __hip_bfloat16* __restrict__ WT,
    const float* __restrict__ bias, void* __restrict__ Cout,
    int M, int N, int K, int mode,
    __hip_bfloat16* __restrict__ o_vb, float* __restrict__ o_off, float* __restrict__ o_aw)
{
    __shared__ __hip_bfloat16 sA[128 * BK];   // [row][k] row-major, 8 KB
    __shared__ __hip_bfloat16 sB[128 * BK];   // [n][k] row-major, 8 KB

    const int tid  = threadIdx.x;
    const int bm   = blockIdx.y * 128;
    const int bn   = blockIdx.x * 128;
    const int lane = tid & 63;
    const int w    = tid >> 6;
    const int wr   = w >> 1, wc = w & 1;
    const int l15  = lane & 15, quad = lane >> 4;

    const int srow  = tid >> 2;
    const int chunk = tid & 3;
    int ga0 = bm + srow;      if (ga0 >= M) ga0 = M - 1;
    int ga1 = bm + srow + 64; if (ga1 >= M) ga1 = M - 1;
    const __hip_bfloat16* Ap0 = A  + (size_t)ga0 * K + chunk * 8;
    const __hip_bfloat16* Ap1 = A  + (size_t)ga1 * K + chunk * 8;
    const __hip_bfloat16* Bp0 = WT + (size_t)(bn + srow) * K + chunk * 8;
    const __hip_bfloat16* Bp1 = WT + (size_t)(bn + srow + 64) * K + chunk * 8;
    __hip_bfloat16* sAd0 = sA + tid * 8;
    __hip_bfloat16* sAd1 = sA + 64 * BK + tid * 8;
    __hip_bfloat16* sBd0 = sB + tid * 8;
    __hip_bfloat16* sBd1 = sB + 64 * BK + tid * 8;

    f32x4 acc[4][4];
    #pragma unroll
    for (int i = 0; i < 4; ++i)
        #pragma unroll
        for (int j = 0; j < 4; ++j) acc[i][j] = (f32x4)0.f;

    for (int k0 = 0; k0 < K; k0 += BK) {
        __syncthreads();
        async16(Ap0 + k0, sAd0);
        async16(Ap1 + k0, sAd1);
        async16(Bp0 + k0, sBd0);
        async16(Bp1 + k0, sBd1);
        __syncthreads();

        bf16x8 a[4], b[4];
        #pragma unroll
        for (int mt = 0; mt < 4; ++mt)
            a[mt] = *(const bf16x8*)&sA[(wr * 64 + mt * 16 + l15) * BK + quad * 8];
        #pragma unroll
        for (int nt = 0; nt < 4; ++nt)
            b[nt] = *(const bf16x8*)&sB[(wc * 64 + nt * 16 + l15) * BK + quad * 8];
        #pragma unroll
        for (int mt = 0; mt < 4; ++mt)
            #pragma unroll
            for (int nt = 0; nt < 4; ++nt)
                acc[mt][nt] = __builtin_amdgcn_mfma_f32_16x16x32_bf16(
                    a[mt], b[nt], acc[mt][nt], 0, 0, 0);
    }

    #pragma unroll
    for (int mt = 0; mt < 4; ++mt) {
        #pragma unroll
        for (int nt = 0; nt < 4; ++nt) {
            const int col = bn + wc * 64 + nt * 16 + l15;
            const float bz = bias[col];
            #pragma unroll
            for (int r = 0; r < 4; ++r) {
                const int row = bm + wr * 64 + mt * 16 + quad * 4 + r;
                if (row >= M) continue;
                float vv = acc[mt][nt][r] + bz;
                if (mode == 0) {
                    ((float*)Cout)[(size_t)row * N + col] = vv;
                } else if (mode == 1) {
                    if (col < 256) {
                        // head-major: idx = ((b*8+h)*NKEYS + local_row)*32 + d
                        // row is global (includes +NKEYS for b=1), so use b*7:
                        const int b = (row >= NKEYS) ? 1 : 0;
                        const int h = col >> 5, d = col & 31;
                        o_vb[((size_t)(b * 7 + h) * NKEYS + row) * 32 + d] = __float2bfloat16(vv);
                    } else if (col < 512) {
                        o_off[(size_t)row * 256 + (col - 256)] = vv;
                    } else {
                        o_aw[(size_t)row * 128 + (col - 512)] = vv;
                    }
                } else { // mode 3: bf16 + relu
                    vv = fmaxf(vv, 0.f);
                    ((__hip_bfloat16*)Cout)[(size_t)row * N + col] = __float2bfloat16(vv);
                }
            }
        }
    }
}

// ---------------- weight transpose+convert ----------------
__global__ void convert_wt_k(const float* __restrict__ W, __hip_bfloat16* __restrict__ WT,
                             int K, int N, int rowOff)
{
    const int idx = blockIdx.x * 256 + threadIdx.x;
    if (idx >= K * N) return;
    const int k = idx / N, n = idx % N;
    WT[(size_t)(rowOff + n) * K + k] = __float2bfloat16(W[idx]);
}

__global__ void pack_bias_k(const float* __restrict__ bv, const float* __restrict__ boff,
                            const float* __restrict__ baw, float* __restrict__ dst)
{
    const int i = blockIdx.x * 256 + threadIdx.x;
    if (i < 256) dst[i] = bv[i];
    else if (i < 512) dst[i] = boff[i - 256];
    else if (i < 640) dst[i] = baw[i - 512];
}

__global__ void convert_src_k(const float* __restrict__ src, float* __restrict__ x,
                              __hip_bfloat16* __restrict__ xb)
{
    const int i = blockIdx.x * 256 + threadIdx.x;   // over n/4
    const float4 v = ((const float4*)src)[i];
    ((float4*)x)[i] = v;
    xb[i * 4 + 0] = __float2bfloat16(v.x);
    xb[i * 4 + 1] = __float2bfloat16(v.y);
    xb[i * 4 + 2] = __float2bfloat16(v.z);
    xb[i * 4 + 3] = __float2bfloat16(v.w);
}

// ---------------- deformable-attention sampling, 2-phase, bf16 values ----------------
// Block = 2 queries, 256 threads.
// Phase 1: t -> (qi=t>>7, h=(t>>4)&7, i=t&15): softmax (16-lane shuffle),
//   bilinear weights + corner key-indices once -> LDS.
// Phase 2: t -> (qi=t>>7, h=(t>>4)&7, d2=t&15): one query, 16 samples,
//   4 corners each as __hip_bfloat162 dim-pair loads; weights broadcast from LDS.
__global__ __launch_bounds__(256) void sample_k(
    const __hip_bfloat16* __restrict__ v_bf, // (B*8, NKEYS, 32) bf16 head-major
    const float* __restrict__ offbuf,  // (M,256) col = (h*16+i)*2+xy
    const float* __restrict__ awbuf,   // (M,128) col = h*16+i
    const float* __restrict__ ref,     // (M,4,2)
    __hip_bfloat16* __restrict__ out)  // (M,256)
{
    __shared__ float sw[256][4];
    __shared__ int   sa[256][4];
    const int t  = threadIdx.x;
    const int q0 = blockIdx.x * 2;
    const int qi = t >> 7, h = (t >> 4) & 7;

    // ---- phase 1 ----
    {
        const int i = t & 15;
        const int q = q0 + qi;
        const int l = i >> 2;
        const float logit = awbuf[(size_t)q * 128 + h * 16 + i];
        float mx = logit;
        #pragma unroll
        for (int m = 1; m < 16; m <<= 1) mx = fmaxf(mx, __shfl_xor(mx, m, 64));
        const float e = __expf(logit - mx);
        float s = e;
        #pragma unroll
        for (int m = 1; m < 16; m <<= 1) s += __shfl_xor(s, m, 64);
        const float aw = e / s;

        const int ww = (l == 0) ? 100 : (l == 1) ? 50 : (l == 2) ? 25 : 13;
        const int ls = (l == 0) ? 0 : (l == 1) ? 10000 : (l == 2) ? 12500 : 13125;
        const int b  = (q >= NKEYS) ? 1 : 0;
        const int slab = (b * 8 + h) * NKEYS + ls;

        const float2 off = *(const float2*)&offbuf[(size_t)q * 256 + h * 32 + i * 2];
        const float2 rf  = *(const float2*)&ref[(size_t)q * 8 + l * 2];
        const float x = rf.x * (float)ww + off.x - 0.5f;
        const float y = rf.y * (float)ww + off.y - 0.5f;   // ww==hh per level
        const float x0f = floorf(x), y0f = floorf(y);
        const float lx = x - x0f, ly = y - y0f;
        const int x0 = (int)x0f, y0 = (int)y0f;
        const bool x0ok = (x0 >= 0) & (x0 < ww);
        const bool x1ok = (x0 + 1 >= 0) & (x0 + 1 < ww);
        const bool y0ok = (y0 >= 0) & (y0 < ww);
        const bool y1ok = (y0 + 1 >= 0) & (y0 + 1 < ww);

        float w00 = (1.f - lx) * (1.f - ly) * aw;
        float w01 = lx * (1.f - ly) * aw;
        float w10 = (1.f - lx) * ly * aw;
        float w11 = lx * ly * aw;
        int a00 = slab + y0 * ww + x0;
        int a01 = a00 + 1;
        int a10 = a00 + ww;
        int a11 = a10 + 1;
        if (!(y0ok & x0ok)) { w00 = 0.f; a00 = 0; }
        if (!(y0ok & x1ok)) { w01 = 0.f; a01 = 0; }
        if (!(y1ok & x0ok)) { w10 = 0.f; a10 = 0; }
        if (!(y1ok & x1ok)) { w11 = 0.f; a11 = 0; }

        sw[t][0] = w00; sw[t][1] = w01; sw[t][2] = w10; sw[t][3] = w11;
        sa[t][0] = a00; sa[t][1] = a01; sa[t][2] = a10; sa[t][3] = a11;
    }
    __syncthreads();

    // ---- phase 2: (qi, h, dim-pair d2) ----
    const int d2 = t & 15;
    const int ebase = qi * 128 + h * 16;
    float acc0 = 0.f, acc1 = 0.f;
    #pragma unroll
    for (int i = 0; i < 16; ++i) {
        const f32x4 wv = *(const f32x4*)sw[ebase + i];
        const int4  av = *(const int4*)sa[ebase + i];
        const __hip_bfloat162 p0 = *(const __hip_bfloat162*)&v_bf[(size_t)av.x * 32 + d2 * 2];
        const __hip_bfloat162 p1 = *(const __hip_bfloat162*)&v_bf[(size_t)av.y * 32 + d2 * 2];
        const __hip_bfloat162 p2 = *(const __hip_bfloat162*)&v_bf[(size_t)av.z * 32 + d2 * 2];
        const __hip_bfloat162 p3 = *(const __hip_bfloat162*)&v_bf[(size_t)av.w * 32 + d2 * 2];
        acc0 += wv[0] * __bfloat162float(p0.x); acc1 += wv[0] * __bfloat162float(p0.y);
        acc0 += wv[1] * __bfloat162float(p1.x); acc1 += wv[1] * __bfloat162float(p1.y);
        acc0 += wv[2] * __bfloat162float(p2.x); acc1 += wv[2] * __bfloat162float(p2.y);
        acc0 += wv[3] * __bfloat162float(p3.x); acc1 += wv[3] * __bfloat162float(p3.y);
    }
    __hip_bfloat162 ov;
    ov.x = __float2bfloat16(acc0);
    ov.y = __float2bfloat16(acc1);
    *(__hip_bfloat162*)&out[(size_t)(q0 + qi) * 256 + h * 32 + d2 * 2] = ov;
}

// ---------------- residual + LayerNorm (writes fp32 x AND bf16 xb) ----------------
__global__ __launch_bounds__(64) void add_ln_k(
    const float* __restrict__ x, const float* __restrict__ r,
    const float* __restrict__ g, const float* __restrict__ bta,
    float* __restrict__ out, __hip_bfloat16* __restrict__ outb)
{
    const int row = blockIdx.x;
    const int t = threadIdx.x;
    const size_t base = (size_t)row * 256 + t * 4;
    const float4 xv = *(const float4*)(x + base);
    const float4 rv = *(const float4*)(r + base);
    float v[4] = {xv.x + rv.x, xv.y + rv.y, xv.z + rv.z, xv.w + rv.w};
    float s = v[0] + v[1] + v[2] + v[3];
    #pragma unroll
    for (int o = 32; o > 0; o >>= 1) s += __shfl_xor(s, o, 64);
    const float m = s * (1.f / 256.f);
    float sq = 0.f;
    #pragma unroll
    for (int i = 0; i < 4; ++i) { const float dd = v[i] - m; sq += dd * dd; }
    #pragma unroll
    for (int o = 32; o > 0; o >>= 1) sq += __shfl_xor(sq, o, 64);
    const float rstd = rsqrtf(sq * (1.f / 256.f) + EPSV);
    const float4 gv = *(const float4*)(g + t * 4);
    const float4 bv = *(const float4*)(bta + t * 4);
    float4 o4;
    o4.x = (v[0] - m) * rstd * gv.x + bv.x;
    o4.y = (v[1] - m) * rstd * gv.y + bv.y;
    o4.z = (v[2] - m) * rstd * gv.z + bv.z;
    o4.w = (v[3] - m) * rstd * gv.w + bv.w;
    *(float4*)(out + base) = o4;
    outb[base + 0] = __float2bfloat16(o4.x);
    outb[base + 1] = __float2bfloat16(o4.y);
    outb[base + 2] = __float2bfloat16(o4.z);
    outb[base + 3] = __float2bfloat16(o4.w);
}

// ---------------- host ----------------
extern "C" void kernel_launch(void* const* d_in, const int* in_sizes, int n_in,
                              void* d_out, int out_size, void* d_ws, size_t ws_size,
                              hipStream_t stream)
{
    const float* src  = (const float*)d_in[0];
    const float* ref  = (const float*)d_in[1];
    const float* Woff = (const float*)d_in[4];   // (256,256)
    const float* boff = (const float*)d_in[5];
    const float* Waw  = (const float*)d_in[6];   // (256,128)
    const float* baw  = (const float*)d_in[7];
    const float* Wv   = (const float*)d_in[8];   // (256,256)
    const float* bv   = (const float*)d_in[9];
    const float* Wo   = (const float*)d_in[10];  // (256,256)
    const float* bo   = (const float*)d_in[11];
    const float* ln1g = (const float*)d_in[12];
    const float* ln1b = (const float*)d_in[13];
    const float* Wf1  = (const float*)d_in[14];  // (256,1024)
    const float* bf1  = (const float*)d_in[15];
    const float* Wf2  = (const float*)d_in[16];  // (1024,256)
    const float* bf2  = (const float*)d_in[17];
    const float* ln2g = (const float*)d_in[18];
    const float* ln2b = (const float*)d_in[19];

    float* x = (float*)d_out;                     // (M,256) fp32 running activation

    float* ws = (float*)d_ws;
    float* offbuf = ws;                                   // M*256 f32
    float* awbuf  = offbuf + (size_t)MROWS * 256;         // M*128 f32
    float* obuf   = awbuf  + (size_t)MROWS * 128;         // M*256 f32
    float* bias1  = obuf   + (size_t)MROWS * 256;         // 640 f32
    __hip_bfloat16* v_bf  = (__hip_bfloat16*)(bias1 + 640);   // M*256 bf16 head-major
    __hip_bfloat16* xb    = v_bf  + (size_t)MROWS * 256;  // M*256 bf16
    __hip_bfloat16* attnb = xb    + (size_t)MROWS * 256;  // M*256 bf16
    __hip_bfloat16* hb    = attnb + (size_t)MROWS * 256;  // M*1024 bf16
    __hip_bfloat16* WT1   = hb    + (size_t)MROWS * 1024; // 640*256
    __hip_bfloat16* WTo   = WT1   + 640 * 256;            // 256*256
    __hip_bfloat16* WTf1  = WTo   + 256 * 256;            // 1024*256
    __hip_bfloat16* WTf2  = WTf1  + 1024 * 256;           // 256*1024

    convert_wt_k<<<(256 * 256 + 255) / 256, 256, 0, stream>>>(Wv,   WT1,  256, 256,   0);
    convert_wt_k<<<(256 * 256 + 255) / 256, 256, 0, stream>>>(Woff, WT1,  256, 256, 256);
    convert_wt_k<<<(256 * 128 + 255) / 256, 256, 0, stream>>>(Waw,  WT1,  256, 128, 512);
    convert_wt_k<<<(256 * 256 + 255) / 256, 256, 0, stream>>>(Wo,   WTo,  256, 256,   0);
    convert_wt_k<<<(256 * 1024 + 255) / 256, 256, 0, stream>>>(Wf1, WTf1, 256, 1024,  0);
    convert_wt_k<<<(1024 * 256 + 255) / 256, 256, 0, stream>>>(Wf2, WTf2, 1024, 256,  0);
    pack_bias_k<<<3, 256, 0, stream>>>(bv, boff, baw, bias1);
    convert_src_k<<<(MROWS * 64 + 255) / 256, 256, 0, stream>>>(src, x, xb);

    const int gy = (MROWS + 127) / 128;   // 208
    for (int layer = 0; layer < 6; ++layer) {
        gemm_mfma_k<<<dim3(640 / 128, gy), 256, 0, stream>>>(
            xb, WT1, bias1, nullptr, MROWS, 640, 256, 1, v_bf, offbuf, awbuf);
        sample_k<<<MROWS / 2, 256, 0, stream>>>(v_bf, offbuf, awbuf, ref, attnb);
        gemm_mfma_k<<<dim3(256 / 128, gy), 256, 0, stream>>>(
            attnb, WTo, bo, obuf, MROWS, 256, 256, 0, nullptr, nullptr, nullptr);
        add_ln_k<<<MROWS, 64, 0, stream>>>(x, obuf, ln1g, ln1b, x, xb);
        gemm_mfma_k<<<dim3(1024 / 128, gy), 256, 0, stream>>>(
            xb, WTf1, bf1, hb, MROWS, 1024, 256, 3, nullptr, nullptr, nullptr);
        gemm_mfma_k<<<dim3(256 / 128, gy), 256, 0, stream>>>(
            hb, WTf2, bf2, obuf, MROWS, 256, 1024, 0, nullptr, nullptr, nullptr);
        add_ln_k<<<MROWS, 64, 0, stream>>>(x, obuf, ln2g, ln2b, x, xb);
    }
}

// Round 6
// 1280.609 us; speedup vs baseline: 4.3185x; 1.1437x over previous
//
#include <hip/hip_runtime.h>
#include <hip/hip_bf16.h>
#include <math.h>

// ---------------- static problem config ----------------
#define NKEYS 13294
#define BATCH 2
#define MROWS (BATCH * NKEYS)   // 26588
#define EDIM  256
#define FDIM  1024
#define EPSV  1e-5f

typedef __bf16 bf16x8 __attribute__((ext_vector_type(8)));
typedef float  f32x4  __attribute__((ext_vector_type(4)));

__device__ __forceinline__ void async16(const void* g, void* l) {
    __builtin_amdgcn_global_load_lds(
        (const __attribute__((address_space(1))) void*)g,
        (__attribute__((address_space(3))) void*)l, 16, 0, 0);
}

// ---------------- bf16 MFMA GEMM: C = A(MxK,bf16) @ WT(NxK,bf16)^T + bias ----------------
// Tile BM=64 x BN=128, BK=32, double-buffered LDS (1 barrier/iter), 256 threads,
// 4 waves as 2x2 of 32x64, 16x16x32 MFMA.
// MODE 0: bf16 out (stride N).  MODE 3: bf16 out + ReLU.
// MODE 1: split fused store (N=640): col<256 -> v_bf head-major bf16;
//         col<512 -> o_off bf16 (stride 256); else -> o_aw bf16 (stride 128).
template<int MODE>
__global__ __launch_bounds__(256, 4) void gemm_mfma_k(
    const __hip_bfloat16* __restrict__ A, const __hip_bfloat16* __restrict__ WT,
    const float* __restrict__ bias, __hip_bfloat16* __restrict__ Cout,
    int M, int N, int K,
    __hip_bfloat16* __restrict__ o_vb, __hip_bfloat16* __restrict__ o_off,
    __hip_bfloat16* __restrict__ o_aw)
{
    constexpr int BM = 64, BN = 128, BKc = 32;
    constexpr int SM = (BM + BN) * BKc;            // 6144 elems = 12 KB / buffer
    __shared__ __hip_bfloat16 smem[2 * SM];        // 24 KB

    const int tid  = threadIdx.x;
    const int bm   = blockIdx.y * BM;
    const int bn   = blockIdx.x * BN;
    const int lane = tid & 63;
    const int w    = tid >> 6;
    const int wr   = w >> 1, wc = w & 1;
    const int l15  = lane & 15, quad = lane >> 4;

    // staging: 3 rounds x 256 threads x 16 B = (64+128)*32*2 B
    int arow = bm + (tid >> 2); if (arow >= M) arow = M - 1;
    const int kc8 = (tid & 3) * 8;
    const __hip_bfloat16* gA  = A  + (size_t)arow * K + kc8;
    const __hip_bfloat16* gB0 = WT + (size_t)(bn + (tid >> 2)) * K + kc8;
    const __hip_bfloat16* gB1 = WT + (size_t)(bn + 64 + (tid >> 2)) * K + kc8;
    const int oA  = tid * 8;
    const int oB0 = BM * BKc + tid * 8;
    const int oB1 = BM * BKc + 64 * BKc + tid * 8;

    f32x4 acc[2][4];
    #pragma unroll
    for (int i = 0; i < 2; ++i)
        #pragma unroll
        for (int j = 0; j < 4; ++j) acc[i][j] = (f32x4)0.f;

    const int T = K / BKc;
    // prologue: tile 0 -> buf 0
    async16(gA,  smem + oA);
    async16(gB0, smem + oB0);
    async16(gB1, smem + oB1);

    for (int it = 0; it < T; ++it) {
        __syncthreads();   // drains vmcnt(0): buf[it&1] ready; all waves done reading buf[(it+1)&1]
        if (it + 1 < T) {
            const int nxt = ((it + 1) & 1) * SM;
            const int ko  = (it + 1) * BKc;
            async16(gA  + ko, smem + nxt + oA);
            async16(gB0 + ko, smem + nxt + oB0);
            async16(gB1 + ko, smem + nxt + oB1);
        }
        const __hip_bfloat16* sA = smem + (it & 1) * SM;
        const __hip_bfloat16* sB = sA + BM * BKc;

        bf16x8 a[2], b[4];
        #pragma unroll
        for (int mt = 0; mt < 2; ++mt)
            a[mt] = *(const bf16x8*)&sA[(wr * 32 + mt * 16 + l15) * BKc + quad * 8];
        #pragma unroll
        for (int nt = 0; nt < 4; ++nt)
            b[nt] = *(const bf16x8*)&sB[(wc * 64 + nt * 16 + l15) * BKc + quad * 8];
        #pragma unroll
        for (int mt = 0; mt < 2; ++mt)
            #pragma unroll
            for (int nt = 0; nt < 4; ++nt)
                acc[mt][nt] = __builtin_amdgcn_mfma_f32_16x16x32_bf16(
                    a[mt], b[nt], acc[mt][nt], 0, 0, 0);
    }

    // epilogue: row = bm + wr*32 + mt*16 + quad*4 + r ; col = bn + wc*64 + nt*16 + l15
    #pragma unroll
    for (int mt = 0; mt < 2; ++mt) {
        #pragma unroll
        for (int nt = 0; nt < 4; ++nt) {
            const int col = bn + wc * 64 + nt * 16 + l15;
            const float bz = bias[col];
            #pragma unroll
            for (int r = 0; r < 4; ++r) {
                const int row = bm + wr * 32 + mt * 16 + quad * 4 + r;
                if (row >= M) continue;
                float vv = acc[mt][nt][r] + bz;
                if (MODE == 1) {
                    if (col < 256) {
                        // head-major: ((b*8+h)*NKEYS + row-b*NKEYS)*32+d == ((b*7+h)*NKEYS + row)*32+d
                        const int b = (row >= NKEYS) ? 1 : 0;
                        const int h = col >> 5, d = col & 31;
                        o_vb[((size_t)(b * 7 + h) * NKEYS + row) * 32 + d] = __float2bfloat16(vv);
                    } else if (col < 512) {
                        o_off[(size_t)row * 256 + (col - 256)] = __float2bfloat16(vv);
                    } else {
                        o_aw[(size_t)row * 128 + (col - 512)] = __float2bfloat16(vv);
                    }
                } else {
                    if (MODE == 3) vv = fmaxf(vv, 0.f);
                    Cout[(size_t)row * N + col] = __float2bfloat16(vv);
                }
            }
        }
    }
}

// ---------------- weight transpose+convert ----------------
__global__ void convert_wt_k(const float* __restrict__ W, __hip_bfloat16* __restrict__ WT,
                             int K, int N, int rowOff)
{
    const int idx = blockIdx.x * 256 + threadIdx.x;
    if (idx >= K * N) return;
    const int k = idx / N, n = idx % N;
    WT[(size_t)(rowOff + n) * K + k] = __float2bfloat16(W[idx]);
}

__global__ void pack_bias_k(const float* __restrict__ bv, const float* __restrict__ boff,
                            const float* __restrict__ baw, float* __restrict__ dst)
{
    const int i = blockIdx.x * 256 + threadIdx.x;
    if (i < 256) dst[i] = bv[i];
    else if (i < 512) dst[i] = boff[i - 256];
    else if (i < 640) dst[i] = baw[i - 512];
}

__global__ void convert_src_k(const float* __restrict__ src, float* __restrict__ x,
                              __hip_bfloat16* __restrict__ xb)
{
    const int i = blockIdx.x * 256 + threadIdx.x;   // over n/4
    const float4 v = ((const float4*)src)[i];
    ((float4*)x)[i] = v;
    xb[i * 4 + 0] = __float2bfloat16(v.x);
    xb[i * 4 + 1] = __float2bfloat16(v.y);
    xb[i * 4 + 2] = __float2bfloat16(v.z);
    xb[i * 4 + 3] = __float2bfloat16(v.w);
}

// ---------------- deformable-attention sampling, 2-phase, all-bf16 inputs ----------------
__global__ __launch_bounds__(256) void sample_k(
    const __hip_bfloat16* __restrict__ v_bf, // (B*8, NKEYS, 32) bf16 head-major
    const __hip_bfloat16* __restrict__ offb, // (M,256) bf16
    const __hip_bfloat16* __restrict__ awb,  // (M,128) bf16
    const float* __restrict__ ref,           // (M,4,2)
    __hip_bfloat16* __restrict__ out)        // (M,256)
{
    __shared__ float sw[256][4];
    __shared__ int   sa[256][4];
    const int t  = threadIdx.x;
    const int q0 = blockIdx.x * 2;
    const int qi = t >> 7, h = (t >> 4) & 7;

    // ---- phase 1: (qi, h, i) ----
    {
        const int i = t & 15;
        const int q = q0 + qi;
        const int l = i >> 2;
        const float logit = __bfloat162float(awb[(size_t)q * 128 + h * 16 + i]);
        float mx = logit;
        #pragma unroll
        for (int m = 1; m < 16; m <<= 1) mx = fmaxf(mx, __shfl_xor(mx, m, 64));
        const float e = __expf(logit - mx);
        float s = e;
        #pragma unroll
        for (int m = 1; m < 16; m <<= 1) s += __shfl_xor(s, m, 64);
        const float aw = e / s;

        const int ww = (l == 0) ? 100 : (l == 1) ? 50 : (l == 2) ? 25 : 13;
        const int ls = (l == 0) ? 0 : (l == 1) ? 10000 : (l == 2) ? 12500 : 13125;
        const int b  = (q >= NKEYS) ? 1 : 0;
        const int slab = (b * 8 + h) * NKEYS + ls;

        const __hip_bfloat162 ofp = *(const __hip_bfloat162*)&offb[(size_t)q * 256 + h * 32 + i * 2];
        const float2 rf = *(const float2*)&ref[(size_t)q * 8 + l * 2];
        const float x = rf.x * (float)ww + __bfloat162float(ofp.x) - 0.5f;
        const float y = rf.y * (float)ww + __bfloat162float(ofp.y) - 0.5f;  // ww==hh per level
        const float x0f = floorf(x), y0f = floorf(y);
        const float lx = x - x0f, ly = y - y0f;
        const int x0 = (int)x0f, y0 = (int)y0f;
        const bool x0ok = (x0 >= 0) & (x0 < ww);
        const bool x1ok = (x0 + 1 >= 0) & (x0 + 1 < ww);
        const bool y0ok = (y0 >= 0) & (y0 < ww);
        const bool y1ok = (y0 + 1 >= 0) & (y0 + 1 < ww);

        float w00 = (1.f - lx) * (1.f - ly) * aw;
        float w01 = lx * (1.f - ly) * aw;
        float w10 = (1.f - lx) * ly * aw;
        float w11 = lx * ly * aw;
        int a00 = slab + y0 * ww + x0;
        int a01 = a00 + 1;
        int a10 = a00 + ww;
        int a11 = a10 + 1;
        if (!(y0ok & x0ok)) { w00 = 0.f; a00 = 0; }
        if (!(y0ok & x1ok)) { w01 = 0.f; a01 = 0; }
        if (!(y1ok & x0ok)) { w10 = 0.f; a10 = 0; }
        if (!(y1ok & x1ok)) { w11 = 0.f; a11 = 0; }

        sw[t][0] = w00; sw[t][1] = w01; sw[t][2] = w10; sw[t][3] = w11;
        sa[t][0] = a00; sa[t][1] = a01; sa[t][2] = a10; sa[t][3] = a11;
    }
    __syncthreads();

    // ---- phase 2: (qi, h, dim-pair d2) ----
    const int d2 = t & 15;
    const int ebase = qi * 128 + h * 16;
    float acc0 = 0.f, acc1 = 0.f;
    #pragma unroll
    for (int i = 0; i < 16; ++i) {
        const f32x4 wv = *(const f32x4*)sw[ebase + i];
        const int4  av = *(const int4*)sa[ebase + i];
        const __hip_bfloat162 p0 = *(const __hip_bfloat162*)&v_bf[(size_t)av.x * 32 + d2 * 2];
        const __hip_bfloat162 p1 = *(const __hip_bfloat162*)&v_bf[(size_t)av.y * 32 + d2 * 2];
        const __hip_bfloat162 p2 = *(const __hip_bfloat162*)&v_bf[(size_t)av.z * 32 + d2 * 2];
        const __hip_bfloat162 p3 = *(const __hip_bfloat162*)&v_bf[(size_t)av.w * 32 + d2 * 2];
        acc0 += wv[0] * __bfloat162float(p0.x); acc1 += wv[0] * __bfloat162float(p0.y);
        acc0 += wv[1] * __bfloat162float(p1.x); acc1 += wv[1] * __bfloat162float(p1.y);
        acc0 += wv[2] * __bfloat162float(p2.x); acc1 += wv[2] * __bfloat162float(p2.y);
        acc0 += wv[3] * __bfloat162float(p3.x); acc1 += wv[3] * __bfloat162float(p3.y);
    }
    __hip_bfloat162 ov;
    ov.x = __float2bfloat16(acc0);
    ov.y = __float2bfloat16(acc1);
    *(__hip_bfloat162*)&out[(size_t)(q0 + qi) * 256 + h * 32 + d2 * 2] = ov;
}

// ---------------- residual(bf16) + LayerNorm (writes fp32 x AND bf16 xb) ----------------
__global__ __launch_bounds__(64) void add_ln_k(
    const float* __restrict__ x, const __hip_bfloat16* __restrict__ rb,
    const float* __restrict__ g, const float* __restrict__ bta,
    float* __restrict__ out, __hip_bfloat16* __restrict__ outb)
{
    const int row = blockIdx.x;
    const int t = threadIdx.x;
    const size_t base = (size_t)row * 256 + t * 4;
    const float4 xv = *(const float4*)(x + base);
    const __hip_bfloat162 r01 = *(const __hip_bfloat162*)(rb + base);
    const __hip_bfloat162 r23 = *(const __hip_bfloat162*)(rb + base + 2);
    float v[4] = {xv.x + __bfloat162float(r01.x), xv.y + __bfloat162float(r01.y),
                  xv.z + __bfloat162float(r23.x), xv.w + __bfloat162float(r23.y)};
    float s = v[0] + v[1] + v[2] + v[3];
    #pragma unroll
    for (int o = 32; o > 0; o >>= 1) s += __shfl_xor(s, o, 64);
    const float m = s * (1.f / 256.f);
    float sq = 0.f;
    #pragma unroll
    for (int i = 0; i < 4; ++i) { const float dd = v[i] - m; sq += dd * dd; }
    #pragma unroll
    for (int o = 32; o > 0; o >>= 1) sq += __shfl_xor(sq, o, 64);
    const float rstd = rsqrtf(sq * (1.f / 256.f) + EPSV);
    const float4 gv = *(const float4*)(g + t * 4);
    const float4 bv = *(const float4*)(bta + t * 4);
    float4 o4;
    o4.x = (v[0] - m) * rstd * gv.x + bv.x;
    o4.y = (v[1] - m) * rstd * gv.y + bv.y;
    o4.z = (v[2] - m) * rstd * gv.z + bv.z;
    o4.w = (v[3] - m) * rstd * gv.w + bv.w;
    *(float4*)(out + base) = o4;
    outb[base + 0] = __float2bfloat16(o4.x);
    outb[base + 1] = __float2bfloat16(o4.y);
    outb[base + 2] = __float2bfloat16(o4.z);
    outb[base + 3] = __float2bfloat16(o4.w);
}

// ---------------- host ----------------
extern "C" void kernel_launch(void* const* d_in, const int* in_sizes, int n_in,
                              void* d_out, int out_size, void* d_ws, size_t ws_size,
                              hipStream_t stream)
{
    const float* src  = (const float*)d_in[0];
    const float* ref  = (const float*)d_in[1];
    const float* Woff = (const float*)d_in[4];   // (256,256)
    const float* boff = (const float*)d_in[5];
    const float* Waw  = (const float*)d_in[6];   // (256,128)
    const float* baw  = (const float*)d_in[7];
    const float* Wv   = (const float*)d_in[8];   // (256,256)
    const float* bv   = (const float*)d_in[9];
    const float* Wo   = (const float*)d_in[10];  // (256,256)
    const float* bo   = (const float*)d_in[11];
    const float* ln1g = (const float*)d_in[12];
    const float* ln1b = (const float*)d_in[13];
    const float* Wf1  = (const float*)d_in[14];  // (256,1024)
    const float* bf1  = (const float*)d_in[15];
    const float* Wf2  = (const float*)d_in[16];  // (1024,256)
    const float* bf2  = (const float*)d_in[17];
    const float* ln2g = (const float*)d_in[18];
    const float* ln2b = (const float*)d_in[19];

    float* x = (float*)d_out;                     // (M,256) fp32 running activation

    float* ws = (float*)d_ws;
    float* bias1 = ws;                                    // 640 f32
    __hip_bfloat16* v_bf  = (__hip_bfloat16*)(bias1 + 640);   // M*256 head-major
    __hip_bfloat16* offb  = v_bf  + (size_t)MROWS * 256;  // M*256
    __hip_bfloat16* awb   = offb  + (size_t)MROWS * 256;  // M*128
    __hip_bfloat16* obuf  = awb   + (size_t)MROWS * 128;  // M*256
    __hip_bfloat16* xb    = obuf  + (size_t)MROWS * 256;  // M*256
    __hip_bfloat16* attnb = xb    + (size_t)MROWS * 256;  // M*256
    __hip_bfloat16* hb    = attnb + (size_t)MROWS * 256;  // M*1024
    __hip_bfloat16* WT1   = hb    + (size_t)MROWS * 1024; // 640*256
    __hip_bfloat16* WTo   = WT1   + 640 * 256;            // 256*256
    __hip_bfloat16* WTf1  = WTo   + 256 * 256;            // 1024*256
    __hip_bfloat16* WTf2  = WTf1  + 1024 * 256;           // 256*1024

    convert_wt_k<<<(256 * 256 + 255) / 256, 256, 0, stream>>>(Wv,   WT1,  256, 256,   0);
    convert_wt_k<<<(256 * 256 + 255) / 256, 256, 0, stream>>>(Woff, WT1,  256, 256, 256);
    convert_wt_k<<<(256 * 128 + 255) / 256, 256, 0, stream>>>(Waw,  WT1,  256, 128, 512);
    convert_wt_k<<<(256 * 256 + 255) / 256, 256, 0, stream>>>(Wo,   WTo,  256, 256,   0);
    convert_wt_k<<<(256 * 1024 + 255) / 256, 256, 0, stream>>>(Wf1, WTf1, 256, 1024,  0);
    convert_wt_k<<<(1024 * 256 + 255) / 256, 256, 0, stream>>>(Wf2, WTf2, 1024, 256,  0);
    pack_bias_k<<<3, 256, 0, stream>>>(bv, boff, baw, bias1);
    convert_src_k<<<(MROWS * 64 + 255) / 256, 256, 0, stream>>>(src, x, xb);

    const int gy = (MROWS + 63) / 64;   // 416
    for (int layer = 0; layer < 6; ++layer) {
        gemm_mfma_k<1><<<dim3(640 / 128, gy), 256, 0, stream>>>(
            xb, WT1, bias1, nullptr, MROWS, 640, 256, v_bf, offb, awb);
        sample_k<<<MROWS / 2, 256, 0, stream>>>(v_bf, offb, awb, ref, attnb);
        gemm_mfma_k<0><<<dim3(256 / 128, gy), 256, 0, stream>>>(
            attnb, WTo, bo, obuf, MROWS, 256, 256, nullptr, nullptr, nullptr);
        add_ln_k<<<MROWS, 64, 0, stream>>>(x, obuf, ln1g, ln1b, x, xb);
        gemm_mfma_k<3><<<dim3(1024 / 128, gy), 256, 0, stream>>>(
            xb, WTf1, bf1, hb, MROWS, 1024, 256, nullptr, nullptr, nullptr);
        gemm_mfma_k<0><<<dim3(256 / 128, gy), 256, 0, stream>>>(
            hb, WTf2, bf2, obuf, MROWS, 256, 1024, nullptr, nullptr, nullptr);
        add_ln_k<<<MROWS, 64, 0, stream>>>(x, obuf, ln2g, ln2b, x, xb);
    }
}

// Round 7
// 1190.833 us; speedup vs baseline: 4.6441x; 1.0754x over previous
//
#include <hip/hip_runtime.h>
#include <hip/hip_bf16.h>
#include <math.h>

// ---------------- static problem config ----------------
#define NKEYS 13294
#define BATCH 2
#define MROWS (BATCH * NKEYS)   // 26588
#define EDIM  256
#define FDIM  1024
#define EPSV  1e-5f

typedef __bf16 bf16x8 __attribute__((ext_vector_type(8)));
typedef float  f32x4  __attribute__((ext_vector_type(4)));

__device__ __forceinline__ void async16(const void* g, void* l) {
    __builtin_amdgcn_global_load_lds(
        (const __attribute__((address_space(1))) void*)g,
        (__attribute__((address_space(3))) void*)l, 16, 0, 0);
}

// ---------------- bf16 MFMA GEMM (BM=64 x BN=128, dbuf): C = A @ WT^T + bias ----------------
// MODE 1: split fused store (N=640): col<256 -> v_bf head-major bf16;
//         col<512 -> o_off bf16 (stride 256); else -> o_aw bf16 (stride 128).
// MODE 3: bf16 out + ReLU (stride N).
template<int MODE>
__global__ __launch_bounds__(256, 4) void gemm_mfma_k(
    const __hip_bfloat16* __restrict__ A, const __hip_bfloat16* __restrict__ WT,
    const float* __restrict__ bias, __hip_bfloat16* __restrict__ Cout,
    int M, int N, int K,
    __hip_bfloat16* __restrict__ o_vb, __hip_bfloat16* __restrict__ o_off,
    __hip_bfloat16* __restrict__ o_aw)
{
    constexpr int BM = 64, BN = 128, BKc = 32;
    constexpr int SM = (BM + BN) * BKc;            // 6144 elems = 12 KB / buffer
    __shared__ __hip_bfloat16 smem[2 * SM];        // 24 KB

    const int tid  = threadIdx.x;
    const int bm   = blockIdx.y * BM;
    const int bn   = blockIdx.x * BN;
    const int lane = tid & 63;
    const int w    = tid >> 6;
    const int wr   = w >> 1, wc = w & 1;
    const int l15  = lane & 15, quad = lane >> 4;

    int arow = bm + (tid >> 2); if (arow >= M) arow = M - 1;
    const int kc8 = (tid & 3) * 8;
    const __hip_bfloat16* gA  = A  + (size_t)arow * K + kc8;
    const __hip_bfloat16* gB0 = WT + (size_t)(bn + (tid >> 2)) * K + kc8;
    const __hip_bfloat16* gB1 = WT + (size_t)(bn + 64 + (tid >> 2)) * K + kc8;
    const int oA  = tid * 8;
    const int oB0 = BM * BKc + tid * 8;
    const int oB1 = BM * BKc + 64 * BKc + tid * 8;

    f32x4 acc[2][4];
    #pragma unroll
    for (int i = 0; i < 2; ++i)
        #pragma unroll
        for (int j = 0; j < 4; ++j) acc[i][j] = (f32x4)0.f;

    const int T = K / BKc;
    async16(gA,  smem + oA);
    async16(gB0, smem + oB0);
    async16(gB1, smem + oB1);

    for (int it = 0; it < T; ++it) {
        __syncthreads();
        if (it + 1 < T) {
            const int nxt = ((it + 1) & 1) * SM;
            const int ko  = (it + 1) * BKc;
            async16(gA  + ko, smem + nxt + oA);
            async16(gB0 + ko, smem + nxt + oB0);
            async16(gB1 + ko, smem + nxt + oB1);
        }
        const __hip_bfloat16* sA = smem + (it & 1) * SM;
        const __hip_bfloat16* sB = sA + BM * BKc;

        bf16x8 a[2], b[4];
        #pragma unroll
        for (int mt = 0; mt < 2; ++mt)
            a[mt] = *(const bf16x8*)&sA[(wr * 32 + mt * 16 + l15) * BKc + quad * 8];
        #pragma unroll
        for (int nt = 0; nt < 4; ++nt)
            b[nt] = *(const bf16x8*)&sB[(wc * 64 + nt * 16 + l15) * BKc + quad * 8];
        #pragma unroll
        for (int mt = 0; mt < 2; ++mt)
            #pragma unroll
            for (int nt = 0; nt < 4; ++nt)
                acc[mt][nt] = __builtin_amdgcn_mfma_f32_16x16x32_bf16(
                    a[mt], b[nt], acc[mt][nt], 0, 0, 0);
    }

    #pragma unroll
    for (int mt = 0; mt < 2; ++mt) {
        #pragma unroll
        for (int nt = 0; nt < 4; ++nt) {
            const int col = bn + wc * 64 + nt * 16 + l15;
            const float bz = bias[col];
            #pragma unroll
            for (int r = 0; r < 4; ++r) {
                const int row = bm + wr * 32 + mt * 16 + quad * 4 + r;
                if (row >= M) continue;
                float vv = acc[mt][nt][r] + bz;
                if (MODE == 1) {
                    if (col < 256) {
                        const int b = (row >= NKEYS) ? 1 : 0;
                        const int h = col >> 5, d = col & 31;
                        o_vb[((size_t)(b * 7 + h) * NKEYS + row) * 32 + d] = __float2bfloat16(vv);
                    } else if (col < 512) {
                        o_off[(size_t)row * 256 + (col - 256)] = __float2bfloat16(vv);
                    } else {
                        o_aw[(size_t)row * 128 + (col - 512)] = __float2bfloat16(vv);
                    }
                } else {
                    if (MODE == 3) vv = fmaxf(vv, 0.f);
                    Cout[(size_t)row * N + col] = __float2bfloat16(vv);
                }
            }
        }
    }
}

// ---------------- fused GEMM + residual + LayerNorm ----------------
// BM=32 x BN=256 (full row), dbuf, 4 waves each 32x64 cols.
// out: x fp32 (next residual / final output) and xb bf16 (next GEMM input).
__global__ __launch_bounds__(256, 4) void gemm_ln_k(
    const __hip_bfloat16* __restrict__ A, const __hip_bfloat16* __restrict__ WT,
    const float* __restrict__ bias, const float* __restrict__ xres,
    const float* __restrict__ g, const float* __restrict__ bta,
    float* __restrict__ xout, __hip_bfloat16* __restrict__ xbout,
    int M, int K)
{
    constexpr int BM = 32, BN = 256, BKc = 32;
    constexpr int ROWS = BM + BN;          // 288
    constexpr int SM = ROWS * BKc;         // 9216 elems = 18 KB / buffer
    __shared__ __hip_bfloat16 smem[2 * SM];  // 36 KB

    const int tid  = threadIdx.x;
    const int bm   = blockIdx.x * BM;
    const int lane = tid & 63;
    const int w    = tid >> 6;             // col group (w*64)
    const int l15  = lane & 15, quad = lane >> 4;

    // staging: 5 rounds x 256 threads x 16 B covers 288 rows x 32 k x 2 B
    const int gRow = tid >> 2;
    const int kc8  = (tid & 3) * 8;
    const __hip_bfloat16* gsrc[5];
    int ldsoff[5];
    bool vmask[5];
    #pragma unroll
    for (int rr = 0; rr < 5; ++rr) {
        int grow = gRow + 64 * rr;
        vmask[rr] = (grow < ROWS);
        int gr = vmask[rr] ? grow : 0;
        if (gr < BM) {
            int ar = bm + gr; if (ar >= M) ar = M - 1;
            gsrc[rr] = A + (size_t)ar * K + kc8;
        } else {
            gsrc[rr] = WT + (size_t)(gr - BM) * K + kc8;
        }
        ldsoff[rr] = gr * BKc + kc8;
    }

    f32x4 acc[2][4];
    #pragma unroll
    for (int i = 0; i < 2; ++i)
        #pragma unroll
        for (int j = 0; j < 4; ++j) acc[i][j] = (f32x4)0.f;

    const int T = K / BKc;
    #pragma unroll
    for (int rr = 0; rr < 5; ++rr)
        if (vmask[rr]) async16(gsrc[rr], smem + ldsoff[rr]);

    for (int it = 0; it < T; ++it) {
        __syncthreads();
        if (it + 1 < T) {
            const int nxt = ((it + 1) & 1) * SM;
            const int ko  = (it + 1) * BKc;
            #pragma unroll
            for (int rr = 0; rr < 5; ++rr)
                if (vmask[rr]) async16(gsrc[rr] + ko, smem + nxt + ldsoff[rr]);
        }
        const __hip_bfloat16* sA = smem + (it & 1) * SM;
        const __hip_bfloat16* sB = sA + BM * BKc;

        bf16x8 a[2], b[4];
        #pragma unroll
        for (int mt = 0; mt < 2; ++mt)
            a[mt] = *(const bf16x8*)&sA[(mt * 16 + l15) * BKc + quad * 8];
        #pragma unroll
        for (int nt = 0; nt < 4; ++nt)
            b[nt] = *(const bf16x8*)&sB[(w * 64 + nt * 16 + l15) * BKc + quad * 8];
        #pragma unroll
        for (int mt = 0; mt < 2; ++mt)
            #pragma unroll
            for (int nt = 0; nt < 4; ++nt)
                acc[mt][nt] = __builtin_amdgcn_mfma_f32_16x16x32_bf16(
                    a[mt], b[nt], acc[mt][nt], 0, 0, 0);
    }

    // ---- epilogue: bias + residual, then LN over the full 256-col row ----
    const int colb = w * 64;
    float bz[4], gz[4], bb[4];
    #pragma unroll
    for (int nt = 0; nt < 4; ++nt) {
        const int col = colb + nt * 16 + l15;
        bz[nt] = bias[col]; gz[nt] = g[col]; bb[nt] = bta[col];
    }
    #pragma unroll
    for (int mt = 0; mt < 2; ++mt)
        #pragma unroll
        for (int r = 0; r < 4; ++r) {
            int row = bm + mt * 16 + quad * 4 + r;
            if (row >= M) row = M - 1;
            #pragma unroll
            for (int nt = 0; nt < 4; ++nt)
                acc[mt][nt][r] += bz[nt] + xres[(size_t)row * 256 + colb + nt * 16 + l15];
        }

    __syncthreads();                       // staging LDS now reusable
    float* stats = (float*)smem;           // [4 wgroup][32 row][2]
    #pragma unroll
    for (int mt = 0; mt < 2; ++mt)
        #pragma unroll
        for (int r = 0; r < 4; ++r) {
            float s = 0.f, sq = 0.f;
            #pragma unroll
            for (int nt = 0; nt < 4; ++nt) {
                const float v = acc[mt][nt][r];
                s += v; sq += v * v;
            }
            #pragma unroll
            for (int m = 1; m < 16; m <<= 1) {
                s  += __shfl_xor(s,  m, 64);
                sq += __shfl_xor(sq, m, 64);
            }
            if (l15 == 0) {
                const int rl = mt * 16 + quad * 4 + r;
                stats[(w * 32 + rl) * 2 + 0] = s;
                stats[(w * 32 + rl) * 2 + 1] = sq;
            }
        }
    __syncthreads();

    #pragma unroll
    for (int mt = 0; mt < 2; ++mt)
        #pragma unroll
        for (int r = 0; r < 4; ++r) {
            const int rl  = mt * 16 + quad * 4 + r;
            const int row = bm + rl;
            float s  = stats[rl * 2]     + stats[(32 + rl) * 2]
                     + stats[(64 + rl) * 2] + stats[(96 + rl) * 2];
            float sq = stats[rl * 2 + 1] + stats[(32 + rl) * 2 + 1]
                     + stats[(64 + rl) * 2 + 1] + stats[(96 + rl) * 2 + 1];
            const float mean = s * (1.f / 256.f);
            const float var  = sq * (1.f / 256.f) - mean * mean;
            const float rstd = rsqrtf(var + EPSV);
            if (row < M) {
                #pragma unroll
                for (int nt = 0; nt < 4; ++nt) {
                    const int col = colb + nt * 16 + l15;
                    const float v = (acc[mt][nt][r] - mean) * rstd * gz[nt] + bb[nt];
                    xout[(size_t)row * 256 + col]  = v;
                    xbout[(size_t)row * 256 + col] = __float2bfloat16(v);
                }
            }
        }
}

// ---------------- weight transpose+convert ----------------
__global__ void convert_wt_k(const float* __restrict__ W, __hip_bfloat16* __restrict__ WT,
                             int K, int N, int rowOff)
{
    const int idx = blockIdx.x * 256 + threadIdx.x;
    if (idx >= K * N) return;
    const int k = idx / N, n = idx % N;
    WT[(size_t)(rowOff + n) * K + k] = __float2bfloat16(W[idx]);
}

__global__ void pack_bias_k(const float* __restrict__ bv, const float* __restrict__ boff,
                            const float* __restrict__ baw, float* __restrict__ dst)
{
    const int i = blockIdx.x * 256 + threadIdx.x;
    if (i < 256) dst[i] = bv[i];
    else if (i < 512) dst[i] = boff[i - 256];
    else if (i < 640) dst[i] = baw[i - 512];
}

__global__ void convert_src_k(const float* __restrict__ src, float* __restrict__ x,
                              __hip_bfloat16* __restrict__ xb)
{
    const int i = blockIdx.x * 256 + threadIdx.x;   // over n/4
    const float4 v = ((const float4*)src)[i];
    ((float4*)x)[i] = v;
    xb[i * 4 + 0] = __float2bfloat16(v.x);
    xb[i * 4 + 1] = __float2bfloat16(v.y);
    xb[i * 4 + 2] = __float2bfloat16(v.z);
    xb[i * 4 + 3] = __float2bfloat16(v.w);
}

// ---------------- deformable-attention sampling, 2-phase ----------------
// LDS skew: IDX(qi,h,i) = (qi*8+h)*17 + i  ->  bank-quad = 4*((8qi+h+i)%8),
// distinct for the 4 h-groups of a wave (conflict-free b128 broadcasts).
// Phase 1 stores BYTE offsets (a*64); phase 2 uses 32-bit offset + uniform base.
__global__ __launch_bounds__(256) void sample_k(
    const __hip_bfloat16* __restrict__ v_bf, // (B*8, NKEYS, 32) bf16 head-major
    const __hip_bfloat16* __restrict__ offb, // (M,256) bf16
    const __hip_bfloat16* __restrict__ awb,  // (M,128) bf16
    const float* __restrict__ ref,           // (M,4,2)
    __hip_bfloat16* __restrict__ out)        // (M,256)
{
    __shared__ alignas(16) float sw[272][4];
    __shared__ alignas(16) int   sa[272][4];
    const int t  = threadIdx.x;
    const int q0 = blockIdx.x * 2;
    const int qi = t >> 7, h = (t >> 4) & 7;

    // ---- phase 1: (qi, h, i) ----
    {
        const int i = t & 15;
        const int q = q0 + qi;
        const int l = i >> 2;
        const float logit = __bfloat162float(awb[(size_t)q * 128 + h * 16 + i]);
        float mx = logit;
        #pragma unroll
        for (int m = 1; m < 16; m <<= 1) mx = fmaxf(mx, __shfl_xor(mx, m, 64));
        const float e = __expf(logit - mx);
        float s = e;
        #pragma unroll
        for (int m = 1; m < 16; m <<= 1) s += __shfl_xor(s, m, 64);
        const float aw = e / s;

        const int ww = (l == 0) ? 100 : (l == 1) ? 50 : (l == 2) ? 25 : 13;
        const int ls = (l == 0) ? 0 : (l == 1) ? 10000 : (l == 2) ? 12500 : 13125;
        const int b  = (q >= NKEYS) ? 1 : 0;
        const int slab = (b * 8 + h) * NKEYS + ls;

        const __hip_bfloat162 ofp = *(const __hip_bfloat162*)&offb[(size_t)q * 256 + h * 32 + i * 2];
        const float2 rf = *(const float2*)&ref[(size_t)q * 8 + l * 2];
        const float x = rf.x * (float)ww + __bfloat162float(ofp.x) - 0.5f;
        const float y = rf.y * (float)ww + __bfloat162float(ofp.y) - 0.5f;  // ww==hh per level
        const float x0f = floorf(x), y0f = floorf(y);
        const float lx = x - x0f, ly = y - y0f;
        const int x0 = (int)x0f, y0 = (int)y0f;
        const bool x0ok = (x0 >= 0) & (x0 < ww);
        const bool x1ok = (x0 + 1 >= 0) & (x0 + 1 < ww);
        const bool y0ok = (y0 >= 0) & (y0 < ww);
        const bool y1ok = (y0 + 1 >= 0) & (y0 + 1 < ww);

        float w00 = (1.f - lx) * (1.f - ly) * aw;
        float w01 = lx * (1.f - ly) * aw;
        float w10 = (1.f - lx) * ly * aw;
        float w11 = lx * ly * aw;
        int a00 = slab + y0 * ww + x0;
        int a01 = a00 + 1;
        int a10 = a00 + ww;
        int a11 = a10 + 1;
        if (!(y0ok & x0ok)) { w00 = 0.f; a00 = 0; }
        if (!(y0ok & x1ok)) { w01 = 0.f; a01 = 0; }
        if (!(y1ok & x0ok)) { w10 = 0.f; a10 = 0; }
        if (!(y1ok & x1ok)) { w11 = 0.f; a11 = 0; }

        const int idx = (qi * 8 + h) * 17 + i;
        sw[idx][0] = w00; sw[idx][1] = w01; sw[idx][2] = w10; sw[idx][3] = w11;
        sa[idx][0] = a00 * 64; sa[idx][1] = a01 * 64;   // byte offsets (row = 64 B)
        sa[idx][2] = a10 * 64; sa[idx][3] = a11 * 64;
    }
    __syncthreads();

    // ---- phase 2: (qi, h, dim-pair d2) ----
    const int d2 = t & 15;
    const unsigned d4 = d2 * 4;
    const char* vb = (const char*)v_bf;
    const int ebase = (qi * 8 + h) * 17;
    float acc0 = 0.f, acc1 = 0.f;
    #pragma unroll
    for (int i = 0; i < 16; ++i) {
        const f32x4 wv = *(const f32x4*)sw[ebase + i];
        const int4  av = *(const int4*)sa[ebase + i];
        const unsigned p0 = *(const unsigned*)(vb + ((unsigned)av.x + d4));
        const unsigned p1 = *(const unsigned*)(vb + ((unsigned)av.y + d4));
        const unsigned p2 = *(const unsigned*)(vb + ((unsigned)av.z + d4));
        const unsigned p3 = *(const unsigned*)(vb + ((unsigned)av.w + d4));
        acc0 += wv[0] * __uint_as_float(p0 << 16);
        acc1 += wv[0] * __uint_as_float(p0 & 0xffff0000u);
        acc0 += wv[1] * __uint_as_float(p1 << 16);
        acc1 += wv[1] * __uint_as_float(p1 & 0xffff0000u);
        acc0 += wv[2] * __uint_as_float(p2 << 16);
        acc1 += wv[2] * __uint_as_float(p2 & 0xffff0000u);
        acc0 += wv[3] * __uint_as_float(p3 << 16);
        acc1 += wv[3] * __uint_as_float(p3 & 0xffff0000u);
    }
    __hip_bfloat162 ov;
    ov.x = __float2bfloat16(acc0);
    ov.y = __float2bfloat16(acc1);
    *(__hip_bfloat162*)&out[(size_t)(q0 + qi) * 256 + h * 32 + d2 * 2] = ov;
}

// ---------------- host ----------------
extern "C" void kernel_launch(void* const* d_in, const int* in_sizes, int n_in,
                              void* d_out, int out_size, void* d_ws, size_t ws_size,
                              hipStream_t stream)
{
    const float* src  = (const float*)d_in[0];
    const float* ref  = (const float*)d_in[1];
    const float* Woff = (const float*)d_in[4];   // (256,256)
    const float* boff = (const float*)d_in[5];
    const float* Waw  = (const float*)d_in[6];   // (256,128)
    const float* baw  = (const float*)d_in[7];
    const float* Wv   = (const float*)d_in[8];   // (256,256)
    const float* bv   = (const float*)d_in[9];
    const float* Wo   = (const float*)d_in[10];  // (256,256)
    const float* bo   = (const float*)d_in[11];
    const float* ln1g = (const float*)d_in[12];
    const float* ln1b = (const float*)d_in[13];
    const float* Wf1  = (const float*)d_in[14];  // (256,1024)
    const float* bf1  = (const float*)d_in[15];
    const float* Wf2  = (const float*)d_in[16];  // (1024,256)
    const float* bf2  = (const float*)d_in[17];
    const float* ln2g = (const float*)d_in[18];
    const float* ln2b = (const float*)d_in[19];

    float* x = (float*)d_out;                     // (M,256) fp32 running activation

    float* ws = (float*)d_ws;
    float* bias1 = ws;                                    // 640 f32
    __hip_bfloat16* v_bf  = (__hip_bfloat16*)(bias1 + 640);   // M*256 head-major
    __hip_bfloat16* offb  = v_bf  + (size_t)MROWS * 256;  // M*256
    __hip_bfloat16* awb   = offb  + (size_t)MROWS * 256;  // M*128
    __hip_bfloat16* xb    = awb   + (size_t)MROWS * 128;  // M*256
    __hip_bfloat16* attnb = xb    + (size_t)MROWS * 256;  // M*256
    __hip_bfloat16* hb    = attnb + (size_t)MROWS * 256;  // M*1024
    __hip_bfloat16* WT1   = hb    + (size_t)MROWS * 1024; // 640*256
    __hip_bfloat16* WTo   = WT1   + 640 * 256;            // 256*256
    __hip_bfloat16* WTf1  = WTo   + 256 * 256;            // 1024*256
    __hip_bfloat16* WTf2  = WTf1  + 1024 * 256;           // 256*1024

    convert_wt_k<<<(256 * 256 + 255) / 256, 256, 0, stream>>>(Wv,   WT1,  256, 256,   0);
    convert_wt_k<<<(256 * 256 + 255) / 256, 256, 0, stream>>>(Woff, WT1,  256, 256, 256);
    convert_wt_k<<<(256 * 128 + 255) / 256, 256, 0, stream>>>(Waw,  WT1,  256, 128, 512);
    convert_wt_k<<<(256 * 256 + 255) / 256, 256, 0, stream>>>(Wo,   WTo,  256, 256,   0);
    convert_wt_k<<<(256 * 1024 + 255) / 256, 256, 0, stream>>>(Wf1, WTf1, 256, 1024,  0);
    convert_wt_k<<<(1024 * 256 + 255) / 256, 256, 0, stream>>>(Wf2, WTf2, 1024, 256,  0);
    pack_bias_k<<<3, 256, 0, stream>>>(bv, boff, baw, bias1);
    convert_src_k<<<(MROWS * 64 + 255) / 256, 256, 0, stream>>>(src, x, xb);

    const int gy  = (MROWS + 63) / 64;   // 416  (BM=64 kernels)
    const int gln = (MROWS + 31) / 32;   // 831  (BM=32 fused kernels)
    for (int layer = 0; layer < 6; ++layer) {
        gemm_mfma_k<1><<<dim3(640 / 128, gy), 256, 0, stream>>>(
            xb, WT1, bias1, nullptr, MROWS, 640, 256, v_bf, offb, awb);
        sample_k<<<MROWS / 2, 256, 0, stream>>>(v_bf, offb, awb, ref, attnb);
        gemm_ln_k<<<gln, 256, 0, stream>>>(
            attnb, WTo, bo, x, ln1g, ln1b, x, xb, MROWS, 256);
        gemm_mfma_k<3><<<dim3(1024 / 128, gy), 256, 0, stream>>>(
            xb, WTf1, bf1, hb, MROWS, 1024, 256, nullptr, nullptr, nullptr);
        gemm_ln_k<<<gln, 256, 0, stream>>>(
            hb, WTf2, bf2, x, ln2g, ln2b, x, xb, MROWS, 1024);
    }
}